// Round 2
// baseline (2010.711 us; speedup 1.0000x reference)
//
#include <hip/hip_runtime.h>
#include <stdint.h>

// Problem constants
#define BB 4
#define LLEN 2048
#define DMODEL 2048
#define NH 24
#define DH 64
#define SS 64
#define DI 1536          // NH*DH
#define N2 3072          // 2*DI
#define NP 3096          // NH*(1+2*SS)
#define NP_PAD 3200      // padded to 25*128
#define MROWS 8192       // BB*LLEN

using bf16x8 = __bf16 __attribute__((ext_vector_type(8)));
using f32x4  = float __attribute__((ext_vector_type(4)));

__device__ __forceinline__ unsigned short f2bf(float f) {
  union { float f; unsigned int u; } v; v.f = f;
  unsigned int u = v.u + 0x7fffu + ((v.u >> 16) & 1u);
  return (unsigned short)(u >> 16);
}
__device__ __forceinline__ float bf2f(unsigned short h) {
  union { unsigned int u; float f; } v; v.u = ((unsigned int)h) << 16;
  return v.f;
}

__device__ __forceinline__ void gload16(const void* g, void* l) {
  __builtin_amdgcn_global_load_lds(
    reinterpret_cast<const __attribute__((address_space(1))) void*>(reinterpret_cast<uintptr_t>(g)),
    reinterpret_cast<__attribute__((address_space(3))) void*>((uint32_t)(reinterpret_cast<uintptr_t>(l))),
    16, 0, 0);
}

// ---------------- fp32 -> bf16 weight convert (with zero row padding) ----------
__global__ __launch_bounds__(256) void k_w2bf(const float* __restrict__ s,
                                              unsigned short* __restrict__ d,
                                              int n_src, int n_dst) {
  int i = blockIdx.x * 256 + threadIdx.x;
  if (i < n_dst) d[i] = (i < n_src) ? f2bf(s[i]) : (unsigned short)0;
}

// ---------------- RMSNorm -> bf16 ----------------
__global__ __launch_bounds__(256) void k_rmsnorm(const float* __restrict__ hs,
                                                 const float* __restrict__ w,
                                                 unsigned short* __restrict__ out) {
  const int row = blockIdx.x;
  const int t = threadIdx.x;
  const float* x = hs + (size_t)row * DMODEL;
  float4 v0 = reinterpret_cast<const float4*>(x)[t * 2 + 0];
  float4 v1 = reinterpret_cast<const float4*>(x)[t * 2 + 1];
  float ss = v0.x * v0.x + v0.y * v0.y + v0.z * v0.z + v0.w * v0.w +
             v1.x * v1.x + v1.y * v1.y + v1.z * v1.z + v1.w * v1.w;
#pragma unroll
  for (int o = 32; o; o >>= 1) ss += __shfl_xor(ss, o);
  __shared__ float red[4];
  if ((t & 63) == 0) red[t >> 6] = ss;
  __syncthreads();
  ss = red[0] + red[1] + red[2] + red[3];
  const float r = rsqrtf(ss * (1.0f / DMODEL) + 1.1920928955078125e-07f);
  float4 w0 = reinterpret_cast<const float4*>(w)[t * 2 + 0];
  float4 w1 = reinterpret_cast<const float4*>(w)[t * 2 + 1];
  union { unsigned short u[8]; uint4 v; } pk;
  pk.u[0] = f2bf(v0.x * r * w0.x); pk.u[1] = f2bf(v0.y * r * w0.y);
  pk.u[2] = f2bf(v0.z * r * w0.z); pk.u[3] = f2bf(v0.w * r * w0.w);
  pk.u[4] = f2bf(v1.x * r * w1.x); pk.u[5] = f2bf(v1.y * r * w1.y);
  pk.u[6] = f2bf(v1.z * r * w1.z); pk.u[7] = f2bf(v1.w * r * w1.w);
  *reinterpret_cast<uint4*>(out + (size_t)row * DMODEL + t * 8) = pk.v;
}

// ---------------- bf16 NT GEMM: C[m,n] = sum_k A[m,k]*B[n,k] (+bias, +resid) ----
// EPI 0: C = acc + bias (fp32 out). EPI 2: C = resid + rg*(acc + bias).
template <int EPI>
__global__ __launch_bounds__(256)
void k_gemm(const unsigned short* __restrict__ A, const unsigned short* __restrict__ B,
            const float* __restrict__ bias, float* __restrict__ C,
            const float* __restrict__ resid, const float* __restrict__ gatep,
            int M, int K, int Nout, int ldc) {
  __shared__ alignas(16) unsigned short As[128 * 32];
  __shared__ alignas(16) unsigned short Bs[128 * 32];
  const int tid = threadIdx.x;
  const int l = tid & 63, w = tid >> 6;
  const int m0 = blockIdx.y * 128, n0 = blockIdx.x * 128;
  const int wm = (w >> 1) * 64, wn = (w & 1) * 64;
  const int fr = l & 15, kg = l >> 4;
  f32x4 acc[4][4] = {};
  const int nkt = K >> 5;
  const int row0 = tid >> 2, cc = tid & 3;
  const int row1 = row0 + 64;
  const unsigned short* Ap0 = A + (size_t)(m0 + row0) * K + cc * 8;
  const unsigned short* Ap1 = A + (size_t)(m0 + row1) * K + cc * 8;
  const unsigned short* Bp0 = B + (size_t)(n0 + row0) * K + cc * 8;
  const unsigned short* Bp1 = B + (size_t)(n0 + row1) * K + cc * 8;
  unsigned short* Asl0 = As + ((w * 64) << 3);
  unsigned short* Asl1 = As + ((256 + w * 64) << 3);
  unsigned short* Bsl0 = Bs + ((w * 64) << 3);
  unsigned short* Bsl1 = Bs + ((256 + w * 64) << 3);
  for (int kt = 0; kt < nkt; ++kt) {
    __syncthreads();
    const int k0 = kt << 5;
    gload16(Ap0 + k0, Asl0);
    gload16(Ap1 + k0, Asl1);
    gload16(Bp0 + k0, Bsl0);
    gload16(Bp1 + k0, Bsl1);
    __syncthreads();
    bf16x8 af[4], bfv[4];
#pragma unroll
    for (int fi = 0; fi < 4; ++fi)
      af[fi] = *reinterpret_cast<const bf16x8*>(As + (wm + fi * 16 + fr) * 32 + kg * 8);
#pragma unroll
    for (int fj = 0; fj < 4; ++fj)
      bfv[fj] = *reinterpret_cast<const bf16x8*>(Bs + (wn + fj * 16 + fr) * 32 + kg * 8);
#pragma unroll
    for (int fi = 0; fi < 4; ++fi)
#pragma unroll
      for (int fj = 0; fj < 4; ++fj)
        acc[fi][fj] = __builtin_amdgcn_mfma_f32_16x16x32_bf16(af[fi], bfv[fj], acc[fi][fj], 0, 0, 0);
  }
  const float rg = (EPI == 2) ? gatep[0] : 0.f;
  const int rq = kg * 4;
#pragma unroll
  for (int fj = 0; fj < 4; ++fj) {
    const int col = n0 + wn + fj * 16 + fr;
    if (col >= Nout) continue;
    const float bv = bias[col];
#pragma unroll
    for (int fi = 0; fi < 4; ++fi) {
      const int rowb = m0 + wm + fi * 16 + rq;
#pragma unroll
      for (int r = 0; r < 4; ++r) {
        const size_t o = (size_t)(rowb + r) * ldc + col;
        float v = acc[fi][fj][r] + bv;
        if (EPI == 2) v = resid[o] + rg * v;
        C[o] = v;
      }
    }
  }
}

// ---------------- depthwise causal conv(4) + silu -> bf16 ----------------
__global__ __launch_bounds__(256) void k_dwconv(const float* __restrict__ xz,
                                                const float* __restrict__ cw,
                                                const float* __restrict__ cb,
                                                unsigned short* __restrict__ out) {
  const int idx = blockIdx.x * 256 + threadIdx.x;  // < MROWS*DI
  const int c = idx % DI;
  const int bl = idx / DI;
  const int lpos = bl & (LLEN - 1);
  float acc = cb[c];
  const float* w4 = cw + c * 4;
#pragma unroll
  for (int k = 0; k < 4; ++k) {
    const int ll = lpos - 3 + k;
    if (ll >= 0) acc = fmaf(w4[k], xz[(size_t)(bl - 3 + k) * N2 + c], acc);
  }
  const float s = acc / (1.f + expf(-acc));
  out[idx] = f2bf(s);
}

// ---------------- prep: normalize B/C in-place, compute alpha into dt slot ------
__global__ __launch_bounds__(256) void k_prep(float* __restrict__ xp,
                                              const unsigned short* __restrict__ xc,
                                              const float* __restrict__ A_log,
                                              const float* __restrict__ l2ab,
                                              const float* __restrict__ l2b,
                                              const float* __restrict__ se) {
  const int blk = blockIdx.x;               // MROWS*6
  const int w = threadIdx.x >> 6, lane = threadIdx.x & 63;
  const int bl = blk / 6, hq = blk % 6;
  const int h = hq * 4 + w;
  const size_t pbase = (size_t)bl * NP + h * 129;
  float bs = xp[pbase + 1 + lane];
  float cs = xp[pbase + 65 + lane];
  float xv = bf2f(xc[(size_t)bl * DI + h * DH + lane]);
  float sb = bs * bs, sc = cs * cs, sx = xv;
#pragma unroll
  for (int o = 32; o; o >>= 1) {
    sb += __shfl_xor(sb, o);
    sc += __shfl_xor(sc, o);
    sx += __shfl_xor(sx, o);
  }
  const float nb = fmaxf(sqrtf(sb), 1e-12f);
  const float nc = fmaxf(sqrtf(sc), 1e-12f);
  xp[pbase + 1 + lane] = bs / nb;
  xp[pbase + 65 + lane] = cs / nc;
  const float sumB2 = sb / (nb * nb);
  const float xmean = sx * (1.f / 64.f);
  const float dt = xp[pbase];
  const float sp = (dt > 20.f) ? dt : log1pf(expf(dt));
  const float Ac = fminf(fmaxf(A_log[h], -2.3f), -0.01f);
  const float a = expf(Ac * sp);
  const float one_a = 1.f - a;
  const float pe = one_a * one_a * xmean * xmean * sumB2 * (1.f / 64.f);
  const float ns = pe / (se[h] + 1e-6f);
  const float beta = exp2f(fminf(fmaxf(l2b[h], -2.f), 2.f));
  const float boost = fmaxf(tanhf(beta * ns), 0.f);
  const float ab = 1.f - exp2f(fminf(fmaxf(l2ab[h], -3.32f), -0.015f));
  const float alpha = fminf(fmaxf(ab + (1.f - ab) * boost, 0.01f), 0.999f);
  if (lane == 0) xp[pbase] = alpha;
}

// ---------------- sequential scan, 1 block per (b,h), fused gating -------------
// Writes G = y * silu(z) as bf16 in place over xcg.
__global__ __launch_bounds__(256) void k_scan(const float* __restrict__ xp,
                                              unsigned short* __restrict__ xcg,
                                              const float* __restrict__ xz) {
  const int b = blockIdx.x / NH, h = blockIdx.x % NH;
  const int tid = threadIdx.x, d = tid & 63, sg = tid >> 6;
  __shared__ float bc[2][128];
  __shared__ float red[2][3][64];
  float hreg[16];
#pragma unroll
  for (int j = 0; j < 16; ++j) hreg[j] = 0.f;

  size_t pb = (size_t)(b * LLEN) * NP + h * 129;
  size_t xb = (size_t)(b * LLEN) * DI + h * DH;
  size_t zb = (size_t)(b * LLEN) * N2 + DI + h * DH;
  const size_t PSTR = NP, XSTR = DI, ZSTR = N2;

  const int PF = 4;
  float pfA[PF], pfB[PF], pfX[PF], pfZ[PF];
#pragma unroll
  for (int k = 0; k < PF; ++k) {
    pfA[k] = xp[pb + (size_t)k * PSTR];
    pfB[k] = (tid < 128) ? xp[pb + (size_t)k * PSTR + 1 + tid] : 0.f;
    pfX[k] = bf2f(xcg[xb + (size_t)k * XSTR + d]);
    pfZ[k] = (sg == 0) ? xz[zb + (size_t)k * ZSTR + d] : 0.f;
  }
  float py_prev = 0.f, z_prev = 0.f;

  for (int tt = 0; tt < LLEN; tt += PF) {
#pragma unroll
    for (int k = 0; k < PF; ++k) {
      const int t = tt + k;
      const int cur = t & 1;
      if (tid < 128) bc[cur][tid] = pfB[k];
      if (sg > 0) red[cur][sg - 1][d] = py_prev;
      const float alpha = pfA[k];
      const float xd = pfX[k];
      __syncthreads();
      if (t > 0 && sg == 0) {
        const float y = py_prev + red[cur][0][d] + red[cur][1][d] + red[cur][2][d];
        const float g = y * (z_prev / (1.f + expf(-z_prev)));
        xcg[xb - XSTR + d] = f2bf(g);
      }
      z_prev = pfZ[k];
      if (t + PF < LLEN) {
        pfA[k] = xp[pb + (size_t)PF * PSTR];
        if (tid < 128) pfB[k] = xp[pb + (size_t)PF * PSTR + 1 + tid];
        pfX[k] = bf2f(xcg[xb + (size_t)PF * XSTR + d]);
        if (sg == 0) pfZ[k] = xz[zb + (size_t)PF * ZSTR + d];
      }
      const float t1 = (1.f - alpha) * xd;
      float py = 0.f;
      const float* Bp = &bc[cur][sg * 16];
      const float* Cp = &bc[cur][64 + sg * 16];
#pragma unroll
      for (int j = 0; j < 16; ++j) {
        hreg[j] = alpha * hreg[j] + Bp[j] * t1;
        py = fmaf(Cp[j], hreg[j], py);
      }
      py_prev = py;
      pb += PSTR; xb += XSTR; zb += ZSTR;
    }
  }
  // finalize last step
  if (sg > 0) red[0][sg - 1][d] = py_prev;
  __syncthreads();
  if (sg == 0) {
    const float y = py_prev + red[0][0][d] + red[0][1][d] + red[0][2][d];
    const float g = y * (z_prev / (1.f + expf(-z_prev)));
    xcg[xb - XSTR + d] = f2bf(g);
  }
}

extern "C" void kernel_launch(void* const* d_in, const int* in_sizes, int n_in,
                              void* d_out, int out_size, void* d_ws, size_t ws_size,
                              hipStream_t stream) {
  const float* hs     = (const float*)d_in[0];
  const float* norm_w = (const float*)d_in[1];
  const float* in_w   = (const float*)d_in[2];
  const float* in_b   = (const float*)d_in[3];
  const float* cw     = (const float*)d_in[4];
  const float* cb     = (const float*)d_in[5];
  const float* xw     = (const float*)d_in[6];
  const float* xb     = (const float*)d_in[7];
  const float* A_log  = (const float*)d_in[8];
  const float* l2ab   = (const float*)d_in[9];
  const float* l2b    = (const float*)d_in[10];
  const float* se     = (const float*)d_in[11];
  const float* ow     = (const float*)d_in[12];
  const float* ob     = (const float*)d_in[13];
  const float* rg     = (const float*)d_in[14];
  float* out = (float*)d_out;

  char* ws = (char*)d_ws;
  // slot0 (32MB): xnorm_bf16, later reused for xconv_bf16 / gated G (24MB)
  unsigned short* xnorm = (unsigned short*)(ws);
  unsigned short* wA    = (unsigned short*)(ws + 33554432ull);
  unsigned short* wX    = (unsigned short*)(ws + 46137344ull);
  unsigned short* wO    = (unsigned short*)(ws + 55967744ull);
  float* xz             = (float*)(ws + 62259200ull);
  float* xp             = (float*)(ws + 162922496ull);
  unsigned short* xcg   = xnorm;  // alias, safe after in_proj GEMM consumed xnorm

  // weight conversions (bf16, x_proj padded to 3200 rows)
  k_w2bf<<<(N2 * DMODEL) / 256, 256, 0, stream>>>(in_w, wA, N2 * DMODEL, N2 * DMODEL);
  k_w2bf<<<(NP_PAD * DI) / 256, 256, 0, stream>>>(xw, wX, NP * DI, NP_PAD * DI);
  k_w2bf<<<(DMODEL * DI) / 256, 256, 0, stream>>>(ow, wO, DMODEL * DI, DMODEL * DI);

  // RMSNorm
  k_rmsnorm<<<MROWS, 256, 0, stream>>>(hs, norm_w, xnorm);
  // in_proj: xz = xnorm @ in_w^T + in_b
  k_gemm<0><<<dim3(N2 / 128, MROWS / 128), 256, 0, stream>>>(
      xnorm, wA, in_b, xz, nullptr, nullptr, MROWS, DMODEL, N2, N2);
  // conv + silu -> bf16 (overwrites slot0)
  k_dwconv<<<(MROWS * DI) / 256, 256, 0, stream>>>(xz, cw, cb, xcg);
  // x_proj: xp = xconv @ xw^T + xb
  k_gemm<0><<<dim3(NP_PAD / 128, MROWS / 128), 256, 0, stream>>>(
      xcg, wX, xb, xp, nullptr, nullptr, MROWS, DI, NP, NP);
  // prep: normalize B/C, alpha
  k_prep<<<MROWS * 6, 256, 0, stream>>>(xp, xcg, A_log, l2ab, l2b, se);
  // scan + fused gating (G in place over xcg)
  k_scan<<<BB * NH, 256, 0, stream>>>(xp, xcg, xz);
  // out_proj + residual
  k_gemm<2><<<dim3(DMODEL / 128, MROWS / 128), 256, 0, stream>>>(
      xcg, wO, ob, out, hs, rg, MROWS, DI, DMODEL, DMODEL);
}

// Round 3
// 668.401 us; speedup vs baseline: 3.0082x; 3.0082x over previous
//
#include <hip/hip_runtime.h>
#include <stdint.h>

// Problem constants
#define BB 4
#define LLEN 2048
#define DMODEL 2048
#define NH 24
#define DH 64
#define SS 64
#define DI 1536          // NH*DH
#define N2 3072          // 2*DI
#define NP 3096          // NH*(1+2*SS)
#define NP_PAD 3200      // padded to 25*128
#define MROWS 8192       // BB*LLEN
#define NCHUNK 16
#define QC 128           // chunk length

using bf16x8 = __bf16 __attribute__((ext_vector_type(8)));
using f32x4  = float __attribute__((ext_vector_type(4)));

__device__ __forceinline__ unsigned short f2bf(float f) {
  union { float f; unsigned int u; } v; v.f = f;
  unsigned int u = v.u + 0x7fffu + ((v.u >> 16) & 1u);
  return (unsigned short)(u >> 16);
}
__device__ __forceinline__ float bf2f(unsigned short h) {
  union { unsigned int u; float f; } v; v.u = ((unsigned int)h) << 16;
  return v.f;
}

__device__ __forceinline__ void gload16(const void* g, void* l) {
  __builtin_amdgcn_global_load_lds(
    reinterpret_cast<const __attribute__((address_space(1))) void*>(reinterpret_cast<uintptr_t>(g)),
    reinterpret_cast<__attribute__((address_space(3))) void*>((uint32_t)(reinterpret_cast<uintptr_t>(l))),
    16, 0, 0);
}

// ---------------- fp32 -> bf16 weight convert (with zero row padding) ----------
__global__ __launch_bounds__(256) void k_w2bf(const float* __restrict__ s,
                                              unsigned short* __restrict__ d,
                                              int n_src, int n_dst) {
  int i = blockIdx.x * 256 + threadIdx.x;
  if (i < n_dst) d[i] = (i < n_src) ? f2bf(s[i]) : (unsigned short)0;
}

// ---------------- RMSNorm -> bf16 ----------------
__global__ __launch_bounds__(256) void k_rmsnorm(const float* __restrict__ hs,
                                                 const float* __restrict__ w,
                                                 unsigned short* __restrict__ out) {
  const int row = blockIdx.x;
  const int t = threadIdx.x;
  const float* x = hs + (size_t)row * DMODEL;
  float4 v0 = reinterpret_cast<const float4*>(x)[t * 2 + 0];
  float4 v1 = reinterpret_cast<const float4*>(x)[t * 2 + 1];
  float ss = v0.x * v0.x + v0.y * v0.y + v0.z * v0.z + v0.w * v0.w +
             v1.x * v1.x + v1.y * v1.y + v1.z * v1.z + v1.w * v1.w;
#pragma unroll
  for (int o = 32; o; o >>= 1) ss += __shfl_xor(ss, o);
  __shared__ float red[4];
  if ((t & 63) == 0) red[t >> 6] = ss;
  __syncthreads();
  ss = red[0] + red[1] + red[2] + red[3];
  const float r = rsqrtf(ss * (1.0f / DMODEL) + 1.1920928955078125e-07f);
  float4 w0 = reinterpret_cast<const float4*>(w)[t * 2 + 0];
  float4 w1 = reinterpret_cast<const float4*>(w)[t * 2 + 1];
  union { unsigned short u[8]; uint4 v; } pk;
  pk.u[0] = f2bf(v0.x * r * w0.x); pk.u[1] = f2bf(v0.y * r * w0.y);
  pk.u[2] = f2bf(v0.z * r * w0.z); pk.u[3] = f2bf(v0.w * r * w0.w);
  pk.u[4] = f2bf(v1.x * r * w1.x); pk.u[5] = f2bf(v1.y * r * w1.y);
  pk.u[6] = f2bf(v1.z * r * w1.z); pk.u[7] = f2bf(v1.w * r * w1.w);
  *reinterpret_cast<uint4*>(out + (size_t)row * DMODEL + t * 8) = pk.v;
}

// ---------------- bf16 NT GEMM: C[m,n] = sum_k A[m,k]*B[n,k] (+bias, +resid) ----
template <int EPI>
__global__ __launch_bounds__(256)
void k_gemm(const unsigned short* __restrict__ A, const unsigned short* __restrict__ B,
            const float* __restrict__ bias, float* __restrict__ C,
            const float* __restrict__ resid, const float* __restrict__ gatep,
            int M, int K, int Nout, int ldc) {
  __shared__ alignas(16) unsigned short As[128 * 32];
  __shared__ alignas(16) unsigned short Bs[128 * 32];
  const int tid = threadIdx.x;
  const int l = tid & 63, w = tid >> 6;
  const int m0 = blockIdx.y * 128, n0 = blockIdx.x * 128;
  const int wm = (w >> 1) * 64, wn = (w & 1) * 64;
  const int fr = l & 15, kg = l >> 4;
  f32x4 acc[4][4] = {};
  const int nkt = K >> 5;
  const int row0 = tid >> 2, cc = tid & 3;
  const int row1 = row0 + 64;
  const unsigned short* Ap0 = A + (size_t)(m0 + row0) * K + cc * 8;
  const unsigned short* Ap1 = A + (size_t)(m0 + row1) * K + cc * 8;
  const unsigned short* Bp0 = B + (size_t)(n0 + row0) * K + cc * 8;
  const unsigned short* Bp1 = B + (size_t)(n0 + row1) * K + cc * 8;
  unsigned short* Asl0 = As + ((w * 64) << 3);
  unsigned short* Asl1 = As + ((256 + w * 64) << 3);
  unsigned short* Bsl0 = Bs + ((w * 64) << 3);
  unsigned short* Bsl1 = Bs + ((256 + w * 64) << 3);
  for (int kt = 0; kt < nkt; ++kt) {
    __syncthreads();
    const int k0 = kt << 5;
    gload16(Ap0 + k0, Asl0);
    gload16(Ap1 + k0, Asl1);
    gload16(Bp0 + k0, Bsl0);
    gload16(Bp1 + k0, Bsl1);
    __syncthreads();
    bf16x8 af[4], bfv[4];
#pragma unroll
    for (int fi = 0; fi < 4; ++fi)
      af[fi] = *reinterpret_cast<const bf16x8*>(As + (wm + fi * 16 + fr) * 32 + kg * 8);
#pragma unroll
    for (int fj = 0; fj < 4; ++fj)
      bfv[fj] = *reinterpret_cast<const bf16x8*>(Bs + (wn + fj * 16 + fr) * 32 + kg * 8);
#pragma unroll
    for (int fi = 0; fi < 4; ++fi)
#pragma unroll
      for (int fj = 0; fj < 4; ++fj)
        acc[fi][fj] = __builtin_amdgcn_mfma_f32_16x16x32_bf16(af[fi], bfv[fj], acc[fi][fj], 0, 0, 0);
  }
  const float rg = (EPI == 2) ? gatep[0] : 0.f;
  const int rq = kg * 4;
#pragma unroll
  for (int fj = 0; fj < 4; ++fj) {
    const int col = n0 + wn + fj * 16 + fr;
    if (col >= Nout) continue;
    const float bv = bias[col];
#pragma unroll
    for (int fi = 0; fi < 4; ++fi) {
      const int rowb = m0 + wm + fi * 16 + rq;
#pragma unroll
      for (int r = 0; r < 4; ++r) {
        const size_t o = (size_t)(rowb + r) * ldc + col;
        float v = acc[fi][fj][r] + bv;
        if (EPI == 2) v = resid[o] + rg * v;
        C[o] = v;
      }
    }
  }
}

// ---------------- depthwise causal conv(4) + silu -> bf16 ----------------
__global__ __launch_bounds__(256) void k_dwconv(const float* __restrict__ xz,
                                                const float* __restrict__ cw,
                                                const float* __restrict__ cb,
                                                unsigned short* __restrict__ out) {
  const int idx = blockIdx.x * 256 + threadIdx.x;  // < MROWS*DI
  const int c = idx % DI;
  const int bl = idx / DI;
  const int lpos = bl & (LLEN - 1);
  float acc = cb[c];
  const float* w4 = cw + c * 4;
#pragma unroll
  for (int k = 0; k < 4; ++k) {
    const int ll = lpos - 3 + k;
    if (ll >= 0) acc = fmaf(w4[k], xz[(size_t)(bl - 3 + k) * N2 + c], acc);
  }
  const float s = acc / (1.f + expf(-acc));
  out[idx] = f2bf(s);
}

// ---------------- prep: normalize+pack B/C as bf16 in place, alpha compact ------
// After this kernel, per (b,l,h) row slice of xp (129 floats):
//   [0]      = dt (stale, unused)
//   [1..33)  = 64 bf16 of normalized B (packed 2/dword)
//   [33..65) = 64 bf16 of normalized C
// alpha -> al[(b*NH+h)*LLEN + l]
__global__ __launch_bounds__(256) void k_prep(float* __restrict__ xp,
                                              const unsigned short* __restrict__ xc,
                                              const float* __restrict__ A_log,
                                              const float* __restrict__ l2ab,
                                              const float* __restrict__ l2b,
                                              const float* __restrict__ se,
                                              float* __restrict__ al) {
  const int blk = blockIdx.x;               // MROWS*6
  const int w = threadIdx.x >> 6, lane = threadIdx.x & 63;
  const int bl = blk / 6, hq = blk % 6;
  const int h = hq * 4 + w;
  const size_t pbase = (size_t)bl * NP + h * 129;
  float bs = xp[pbase + 1 + lane];
  float cs = xp[pbase + 65 + lane];
  float xv = bf2f(xc[(size_t)bl * DI + h * DH + lane]);
  float sb = bs * bs, sc = cs * cs, sx = xv;
#pragma unroll
  for (int o = 32; o; o >>= 1) {
    sb += __shfl_xor(sb, o);
    sc += __shfl_xor(sc, o);
    sx += __shfl_xor(sx, o);
  }
  const float nb = fmaxf(sqrtf(sb), 1e-12f);
  const float nc = fmaxf(sqrtf(sc), 1e-12f);
  const float bn = bs / nb, cn = cs / nc;
  // pack bf16 pairs; lanes 0..31 write one dword each (reads already in regs)
  const float blo = __shfl(bn, lane * 2, 64), bhi = __shfl(bn, lane * 2 + 1, 64);
  const float clo = __shfl(cn, lane * 2, 64), chi = __shfl(cn, lane * 2 + 1, 64);
  if (lane < 32) {
    ((unsigned int*)(xp + pbase + 1))[lane]  = (unsigned int)f2bf(blo) | ((unsigned int)f2bf(bhi) << 16);
    ((unsigned int*)(xp + pbase + 33))[lane] = (unsigned int)f2bf(clo) | ((unsigned int)f2bf(chi) << 16);
  }
  const float sumB2 = sb / (nb * nb);
  const float xmean = sx * (1.f / 64.f);
  const float dt = xp[pbase];
  const float sp = (dt > 20.f) ? dt : log1pf(expf(dt));
  const float Ac = fminf(fmaxf(A_log[h], -2.3f), -0.01f);
  const float aa = expf(Ac * sp);
  const float one_a = 1.f - aa;
  const float pe = one_a * one_a * xmean * xmean * sumB2 * (1.f / 64.f);
  const float ns = pe / (se[h] + 1e-6f);
  const float beta = exp2f(fminf(fmaxf(l2b[h], -2.f), 2.f));
  const float boost = fmaxf(tanhf(beta * ns), 0.f);
  const float ab = 1.f - exp2f(fminf(fmaxf(l2ab[h], -3.32f), -0.015f));
  const float alpha = fminf(fmaxf(ab + (1.f - ab) * boost, 0.01f), 0.999f);
  if (lane == 0) {
    const int b = bl >> 11, l = bl & (LLEN - 1);
    al[(((size_t)b * NH + h) << 11) + l] = alpha;
  }
}

// ---------------- chunked scan, stage 1: intra-chunk Y + local state -----------
// One block per (bh, chunk). Computes:
//   Y_intra[t,d] -> xz x-half (cols h*64+d)
//   H_local^T[d,s] (bf16) -> Hbuf[(bh*16+c)*4096 + d*64 + s]
//   Dc[bh*16+c] = exp(lc[127])
__global__ __launch_bounds__(256) void k_chunk1(
    const float* __restrict__ xp, const unsigned short* __restrict__ xcg,
    const float* __restrict__ al, float* __restrict__ xz,
    unsigned short* __restrict__ Hbuf, float* __restrict__ Dc) {
  const int blk = blockIdx.x;          // bh*16 + c
  const int bh = blk >> 4, c = blk & 15;
  const int b = bh / NH, h = bh % NH;
  const int tid = threadIdx.x, w = tid >> 6, lane = tid & 63;
  const int fr = lane & 15, kg = lane >> 4;
  const int rbase = b * LLEN + c * QC;

  __shared__ float lc[QC], ia[QC], escl[QC];
  __shared__ float wtot[2];
  __shared__ alignas(16) unsigned short XT[64][152];   // [d][u]
  __shared__ alignas(16) unsigned short BsT[64][152];  // [s][u] (scaled)
  __shared__ alignas(16) unsigned short Pt[128][88];   // [t][u-local] per u-tile

  // phase 0: alpha -> inclusive cumsum of log
  float a = 1.f, la = 0.f;
  if (tid < QC) { a = al[(size_t)bh * LLEN + c * QC + tid]; la = __logf(a); }
  float s = la;
#pragma unroll
  for (int o = 1; o < 64; o <<= 1) { float t2 = __shfl_up(s, o); if (lane >= o) s += t2; }
  if (tid < QC && lane == 63) wtot[w] = s;
  __syncthreads();
  if (tid < QC) { lc[tid] = s + ((w == 1) ? wtot[0] : 0.f); ia[tid] = 1.f - a; }
  __syncthreads();
  const float lcE = lc[QC - 1];
  if (tid < QC) escl[tid] = __expf(lcE - lc[tid]) * ia[tid];
  if (tid == 0) Dc[blk] = __expf(lcE);
  __syncthreads();

  // phase 1: stage XT (transposed X) and BsT (scaled, transposed B)
  {
    const int r8 = tid >> 3, q8 = tid & 7;
#pragma unroll
    for (int it = 0; it < 4; ++it) {
      const int u = it * 32 + r8;
      uint4 xv = *(const uint4*)(xcg + (size_t)(rbase + u) * DI + h * DH + q8 * 8);
      const unsigned short* xs = (const unsigned short*)&xv;
#pragma unroll
      for (int j = 0; j < 8; ++j) XT[q8 * 8 + j][u] = xs[j];
      const unsigned int* bp = (const unsigned int*)(xp + (size_t)(rbase + u) * NP + h * 129 + 1) + q8 * 4;
      const float e = escl[u];
#pragma unroll
      for (int q = 0; q < 4; ++q) {
        unsigned int dv = bp[q];
        BsT[q8 * 8 + q * 2 + 0][u] = f2bf(bf2f((unsigned short)(dv & 0xffff)) * e);
        BsT[q8 * 8 + q * 2 + 1][u] = f2bf(bf2f((unsigned short)(dv >> 16)) * e);
      }
    }
  }
  // C fragments (A-operand of G) direct from packed global, kept in regs
  bf16x8 cf[2][2];
#pragma unroll
  for (int fi = 0; fi < 2; ++fi)
#pragma unroll
    for (int kk = 0; kk < 2; ++kk) {
      const int t = w * 32 + fi * 16 + fr;
      const unsigned int* p = (const unsigned int*)(xp + (size_t)(rbase + t) * NP + h * 129 + 33) + kk * 16 + kg * 4;
      union { unsigned int u[4]; bf16x8 v; } uv;
      uv.u[0] = p[0]; uv.u[1] = p[1]; uv.u[2] = p[2]; uv.u[3] = p[3];
      cf[fi][kk] = uv.v;
    }
  __syncthreads();

  float lct[2][4];
#pragma unroll
  for (int fi = 0; fi < 2; ++fi)
#pragma unroll
    for (int r = 0; r < 4; ++r) lct[fi][r] = lc[w * 32 + fi * 16 + kg * 4 + r];

  f32x4 yacc[2][4] = {};
  f32x4 hacc[4] = {};
#pragma unroll
  for (int ut = 0; ut < 2; ++ut) {
    // G = C B^T for this u-tile (B frags direct from packed global)
    f32x4 g[2][4] = {};
#pragma unroll
    for (int kk = 0; kk < 2; ++kk)
#pragma unroll
      for (int fj = 0; fj < 4; ++fj) {
        const int u = ut * 64 + fj * 16 + fr;
        const unsigned int* p = (const unsigned int*)(xp + (size_t)(rbase + u) * NP + h * 129 + 1) + kk * 16 + kg * 4;
        union { unsigned int uu[4]; bf16x8 v; } uv;
        uv.uu[0] = p[0]; uv.uu[1] = p[1]; uv.uu[2] = p[2]; uv.uu[3] = p[3];
#pragma unroll
        for (int fi = 0; fi < 2; ++fi)
          g[fi][fj] = __builtin_amdgcn_mfma_f32_16x16x32_bf16(cf[fi][kk], uv.v, g[fi][fj], 0, 0, 0);
      }
    // mask + scale -> Pt (per-wave private rows, no barrier needed)
#pragma unroll
    for (int fi = 0; fi < 2; ++fi)
#pragma unroll
      for (int fj = 0; fj < 4; ++fj) {
        const int u = ut * 64 + fj * 16 + fr;
        const float lcu = lc[u], iau = ia[u];
#pragma unroll
        for (int r = 0; r < 4; ++r) {
          const int t = w * 32 + fi * 16 + kg * 4 + r;
          const float v = (t >= u) ? g[fi][fj][r] * __expf(lct[fi][r] - lcu) * iau : 0.f;
          Pt[t][fj * 16 + fr] = f2bf(v);
        }
      }
    // Y += P @ X^T ; H += Bscl^T @ X^T   (K = 64 per u-tile)
#pragma unroll
    for (int kk = 0; kk < 2; ++kk) {
      bf16x8 xf[4];
#pragma unroll
      for (int fj = 0; fj < 4; ++fj)
        xf[fj] = *(const bf16x8*)&XT[fj * 16 + fr][ut * 64 + kk * 32 + kg * 8];
      bf16x8 pf[2];
#pragma unroll
      for (int fi = 0; fi < 2; ++fi)
        pf[fi] = *(const bf16x8*)&Pt[w * 32 + fi * 16 + fr][kk * 32 + kg * 8];
#pragma unroll
      for (int fi = 0; fi < 2; ++fi)
#pragma unroll
        for (int fj = 0; fj < 4; ++fj)
          yacc[fi][fj] = __builtin_amdgcn_mfma_f32_16x16x32_bf16(pf[fi], xf[fj], yacc[fi][fj], 0, 0, 0);
      const bf16x8 xh = *(const bf16x8*)&XT[w * 16 + fr][ut * 64 + kk * 32 + kg * 8];
#pragma unroll
      for (int fi = 0; fi < 4; ++fi) {
        const bf16x8 bs = *(const bf16x8*)&BsT[fi * 16 + fr][ut * 64 + kk * 32 + kg * 8];
        hacc[fi] = __builtin_amdgcn_mfma_f32_16x16x32_bf16(bs, xh, hacc[fi], 0, 0, 0);
      }
    }
  }
  // epilogue: Y_intra (fp32, xz x-half) and H_local^T (bf16)
#pragma unroll
  for (int fi = 0; fi < 2; ++fi)
#pragma unroll
    for (int fj = 0; fj < 4; ++fj)
#pragma unroll
      for (int r = 0; r < 4; ++r) {
        const int t = w * 32 + fi * 16 + kg * 4 + r;
        const int d = fj * 16 + fr;
        xz[(size_t)(rbase + t) * N2 + h * DH + d] = yacc[fi][fj][r];
      }
  const int dcol = w * 16 + fr;
#pragma unroll
  for (int fi = 0; fi < 4; ++fi) {
    ushort4 pk;
    pk.x = f2bf(hacc[fi][0]); pk.y = f2bf(hacc[fi][1]);
    pk.z = f2bf(hacc[fi][2]); pk.w = f2bf(hacc[fi][3]);
    *(ushort4*)(Hbuf + ((size_t)blk * 64 + dcol) * 64 + fi * 16 + kg * 4) = pk;
  }
}

// ---------------- chunked scan, stage 2: carry across chunks (in place) --------
// Hbuf slot c: in = H_local, out = H_in (state before chunk c)
__global__ __launch_bounds__(256) void k_carry(unsigned short* __restrict__ Hbuf,
                                               const float* __restrict__ Dc) {
  const int bh = blockIdx.x, tid = threadIdx.x;
  float carry[16];
#pragma unroll
  for (int j = 0; j < 16; ++j) carry[j] = 0.f;
  for (int c = 0; c < NCHUNK; ++c) {
    unsigned short* p = Hbuf + (((size_t)(bh * NCHUNK + c)) << 12) + tid * 16;
    const uint4 v0 = *(const uint4*)(p);
    const uint4 v1 = *(const uint4*)(p + 8);
    const unsigned short* hs0 = (const unsigned short*)&v0;
    const unsigned short* hs1 = (const unsigned short*)&v1;
    float hl[16];
#pragma unroll
    for (int j = 0; j < 8; ++j) { hl[j] = bf2f(hs0[j]); hl[8 + j] = bf2f(hs1[j]); }
    uint4 o0, o1;
    unsigned short* os0 = (unsigned short*)&o0;
    unsigned short* os1 = (unsigned short*)&o1;
#pragma unroll
    for (int j = 0; j < 8; ++j) { os0[j] = f2bf(carry[j]); os1[j] = f2bf(carry[8 + j]); }
    *(uint4*)(p) = o0;
    *(uint4*)(p + 8) = o1;
    const float dc = Dc[bh * NCHUNK + c];
#pragma unroll
    for (int j = 0; j < 16; ++j) carry[j] = fmaf(dc, carry[j], hl[j]);
  }
}

// ---------------- chunked scan, stage 3: inter-chunk Y + fused gating ----------
__global__ __launch_bounds__(256) void k_chunk2(
    const float* __restrict__ xp, const float* __restrict__ al,
    const unsigned short* __restrict__ Hbuf, const float* __restrict__ xz,
    unsigned short* __restrict__ xcg) {
  const int blk = blockIdx.x;
  const int bh = blk >> 4, c = blk & 15;
  const int b = bh / NH, h = bh % NH;
  const int tid = threadIdx.x, w = tid >> 6, lane = tid & 63;
  const int fr = lane & 15, kg = lane >> 4;
  const int rbase = b * LLEN + c * QC;
  __shared__ float lc[QC];
  __shared__ float wtot[2];
  float a = 1.f, la = 0.f;
  if (tid < QC) { a = al[(size_t)bh * LLEN + c * QC + tid]; la = __logf(a); }
  float s = la;
#pragma unroll
  for (int o = 1; o < 64; o <<= 1) { float t2 = __shfl_up(s, o); if (lane >= o) s += t2; }
  if (tid < QC && lane == 63) wtot[w] = s;
  __syncthreads();
  if (tid < QC) lc[tid] = s + ((w == 1) ? wtot[0] : 0.f);
  __syncthreads();
  // A frags: C scaled by exp(lc[t])
  bf16x8 cf[2][2];
#pragma unroll
  for (int fi = 0; fi < 2; ++fi) {
    const int t = w * 32 + fi * 16 + fr;
    const float sc = __expf(lc[t]);
#pragma unroll
    for (int kk = 0; kk < 2; ++kk) {
      const unsigned int* p = (const unsigned int*)(xp + (size_t)(rbase + t) * NP + h * 129 + 33) + kk * 16 + kg * 4;
      union { unsigned short us[8]; bf16x8 v; } uv;
#pragma unroll
      for (int q = 0; q < 4; ++q) {
        const unsigned int dv = p[q];
        uv.us[2 * q]     = f2bf(bf2f((unsigned short)(dv & 0xffff)) * sc);
        uv.us[2 * q + 1] = f2bf(bf2f((unsigned short)(dv >> 16)) * sc);
      }
      cf[fi][kk] = uv.v;
    }
  }
  // B frags: H_in^T ([d][s], bf16)
  bf16x8 hf[4][2];
#pragma unroll
  for (int fj = 0; fj < 4; ++fj)
#pragma unroll
    for (int kk = 0; kk < 2; ++kk) {
      const uint4 v = *(const uint4*)(Hbuf + ((size_t)blk * 64 + fj * 16 + fr) * 64 + kk * 32 + kg * 8);
      hf[fj][kk] = *(const bf16x8*)&v;
    }
  f32x4 y[2][4] = {};
#pragma unroll
  for (int kk = 0; kk < 2; ++kk)
#pragma unroll
    for (int fi = 0; fi < 2; ++fi)
#pragma unroll
      for (int fj = 0; fj < 4; ++fj)
        y[fi][fj] = __builtin_amdgcn_mfma_f32_16x16x32_bf16(cf[fi][kk], hf[fj][kk], y[fi][fj], 0, 0, 0);
  // epilogue: add Y_intra, gate with silu(z), write bf16
#pragma unroll
  for (int fi = 0; fi < 2; ++fi)
#pragma unroll
    for (int fj = 0; fj < 4; ++fj)
#pragma unroll
      for (int r = 0; r < 4; ++r) {
        const int t = w * 32 + fi * 16 + kg * 4 + r;
        const int d = fj * 16 + fr;
        const size_t rowg = (size_t)(rbase + t);
        const float yv = y[fi][fj][r] + xz[rowg * N2 + h * DH + d];
        const float zv = xz[rowg * N2 + DI + h * DH + d];
        const float g = yv * (zv / (1.f + __expf(-zv)));
        xcg[rowg * DI + h * DH + d] = f2bf(g);
      }
}

extern "C" void kernel_launch(void* const* d_in, const int* in_sizes, int n_in,
                              void* d_out, int out_size, void* d_ws, size_t ws_size,
                              hipStream_t stream) {
  const float* hs     = (const float*)d_in[0];
  const float* norm_w = (const float*)d_in[1];
  const float* in_w   = (const float*)d_in[2];
  const float* in_b   = (const float*)d_in[3];
  const float* cw     = (const float*)d_in[4];
  const float* cb     = (const float*)d_in[5];
  const float* xw     = (const float*)d_in[6];
  const float* xb     = (const float*)d_in[7];
  const float* A_log  = (const float*)d_in[8];
  const float* l2ab   = (const float*)d_in[9];
  const float* l2b    = (const float*)d_in[10];
  const float* se     = (const float*)d_in[11];
  const float* ow     = (const float*)d_in[12];
  const float* ob     = (const float*)d_in[13];
  const float* rg     = (const float*)d_in[14];
  float* out = (float*)d_out;

  char* ws = (char*)d_ws;
  // layout (max 264.4 MB, same as round 1):
  //   0          xnorm/xcg bf16 (33.5MB)
  //   33554432   wA bf16 (12.58MB) -> reused as Hbuf after in_proj
  //   46137344   wX bf16 (9.8MB)   -> reused: al (0.79MB) + Dc (6KB) after x_proj
  //   55967744   wO bf16 (6.3MB)
  //   62259200   xz fp32 (100.7MB; x-half reused for Y_intra)
  //   162922496  xp fp32 (101.4MB; B/C repacked bf16 in place by k_prep)
  unsigned short* xnorm = (unsigned short*)(ws);
  unsigned short* wA    = (unsigned short*)(ws + 33554432ull);
  unsigned short* wX    = (unsigned short*)(ws + 46137344ull);
  unsigned short* wO    = (unsigned short*)(ws + 55967744ull);
  float* xz             = (float*)(ws + 62259200ull);
  float* xp             = (float*)(ws + 162922496ull);
  unsigned short* xcg   = xnorm;
  unsigned short* Hbuf  = wA;
  float* al             = (float*)(ws + 46137344ull);
  float* Dc             = (float*)(ws + 46137344ull + 786432ull);

  k_w2bf<<<(N2 * DMODEL) / 256, 256, 0, stream>>>(in_w, wA, N2 * DMODEL, N2 * DMODEL);
  k_w2bf<<<(NP_PAD * DI) / 256, 256, 0, stream>>>(xw, wX, NP * DI, NP_PAD * DI);
  k_w2bf<<<(DMODEL * DI) / 256, 256, 0, stream>>>(ow, wO, DMODEL * DI, DMODEL * DI);

  k_rmsnorm<<<MROWS, 256, 0, stream>>>(hs, norm_w, xnorm);
  k_gemm<0><<<dim3(N2 / 128, MROWS / 128), 256, 0, stream>>>(
      xnorm, wA, in_b, xz, nullptr, nullptr, MROWS, DMODEL, N2, N2);
  k_dwconv<<<(MROWS * DI) / 256, 256, 0, stream>>>(xz, cw, cb, xcg);
  k_gemm<0><<<dim3(NP_PAD / 128, MROWS / 128), 256, 0, stream>>>(
      xcg, wX, xb, xp, nullptr, nullptr, MROWS, DI, NP, NP);
  k_prep<<<MROWS * 6, 256, 0, stream>>>(xp, xcg, A_log, l2ab, l2b, se, al);

  // chunked scan (SSD form): intra-chunk -> carry -> inter-chunk+gate
  k_chunk1<<<BB * NH * NCHUNK, 256, 0, stream>>>(xp, xcg, al, xz, Hbuf, Dc);
  k_carry<<<BB * NH, 256, 0, stream>>>(Hbuf, Dc);
  k_chunk2<<<BB * NH * NCHUNK, 256, 0, stream>>>(xp, al, Hbuf, xz, xcg);

  k_gemm<2><<<dim3(DMODEL / 128, MROWS / 128), 256, 0, stream>>>(
      xcg, wO, ob, out, hs, rg, MROWS, DI, DMODEL, DMODEL);
}

// Round 4
// 607.318 us; speedup vs baseline: 3.3108x; 1.1006x over previous
//
#include <hip/hip_runtime.h>
#include <stdint.h>

// Problem constants
#define BB 4
#define LLEN 2048
#define DMODEL 2048
#define NH 24
#define DH 64
#define SS 64
#define DI 1536          // NH*DH
#define N2 3072          // 2*DI
#define NP 3096          // NH*(1+2*SS)
#define NP_PAD 3200      // padded to 25*128
#define MROWS 8192       // BB*LLEN
#define NCHUNK 16
#define QC 128           // chunk length

using bf16x8 = __bf16 __attribute__((ext_vector_type(8)));
using f32x4  = float __attribute__((ext_vector_type(4)));

__device__ __forceinline__ unsigned short f2bf(float f) {
  union { float f; unsigned int u; } v; v.f = f;
  unsigned int u = v.u + 0x7fffu + ((v.u >> 16) & 1u);
  return (unsigned short)(u >> 16);
}
__device__ __forceinline__ float bf2f(unsigned short h) {
  union { unsigned int u; float f; } v; v.u = ((unsigned int)h) << 16;
  return v.f;
}

__device__ __forceinline__ void gload16(const void* g, void* l) {
  __builtin_amdgcn_global_load_lds(
    reinterpret_cast<const __attribute__((address_space(1))) void*>(reinterpret_cast<uintptr_t>(g)),
    reinterpret_cast<__attribute__((address_space(3))) void*>((uint32_t)(reinterpret_cast<uintptr_t>(l))),
    16, 0, 0);
}

// ---------------- fp32 -> bf16 weight convert (with zero row padding) ----------
__global__ __launch_bounds__(256) void k_w2bf(const float* __restrict__ s,
                                              unsigned short* __restrict__ d,
                                              int n_src, int n_dst) {
  int i = blockIdx.x * 256 + threadIdx.x;
  if (i < n_dst) d[i] = (i < n_src) ? f2bf(s[i]) : (unsigned short)0;
}

// ---------------- RMSNorm -> bf16 ----------------
__global__ __launch_bounds__(256) void k_rmsnorm(const float* __restrict__ hs,
                                                 const float* __restrict__ w,
                                                 unsigned short* __restrict__ out) {
  const int row = blockIdx.x;
  const int t = threadIdx.x;
  const float* x = hs + (size_t)row * DMODEL;
  float4 v0 = reinterpret_cast<const float4*>(x)[t * 2 + 0];
  float4 v1 = reinterpret_cast<const float4*>(x)[t * 2 + 1];
  float ss = v0.x * v0.x + v0.y * v0.y + v0.z * v0.z + v0.w * v0.w +
             v1.x * v1.x + v1.y * v1.y + v1.z * v1.z + v1.w * v1.w;
#pragma unroll
  for (int o = 32; o; o >>= 1) ss += __shfl_xor(ss, o);
  __shared__ float red[4];
  if ((t & 63) == 0) red[t >> 6] = ss;
  __syncthreads();
  ss = red[0] + red[1] + red[2] + red[3];
  const float r = rsqrtf(ss * (1.0f / DMODEL) + 1.1920928955078125e-07f);
  float4 w0 = reinterpret_cast<const float4*>(w)[t * 2 + 0];
  float4 w1 = reinterpret_cast<const float4*>(w)[t * 2 + 1];
  union { unsigned short u[8]; uint4 v; } pk;
  pk.u[0] = f2bf(v0.x * r * w0.x); pk.u[1] = f2bf(v0.y * r * w0.y);
  pk.u[2] = f2bf(v0.z * r * w0.z); pk.u[3] = f2bf(v0.w * r * w0.w);
  pk.u[4] = f2bf(v1.x * r * w1.x); pk.u[5] = f2bf(v1.y * r * w1.y);
  pk.u[6] = f2bf(v1.z * r * w1.z); pk.u[7] = f2bf(v1.w * r * w1.w);
  *reinterpret_cast<uint4*>(out + (size_t)row * DMODEL + t * 8) = pk.v;
}

// ---------------- pipelined bf16 NT GEMM (256x128 tile, BK=64, 3-buf ring) -----
// C[m,n] = sum_k A[m,k]*B[n,k] (+bias); EPI 2: C = resid + rg*(acc+bias).
// 512 threads = 8 waves (4M x 2N), per-wave 64x64 output.
// LDS: 3 ring buffers x (A 32KB + B 16KB) = 144KB. Prefetch distance 2 K-tiles,
// counted vmcnt(6) at tile boundary (6 = gloads issued per tile; waits for t+1,
// leaves t+2 in flight). Swizzle: granule q ^= (row&7) on global src + LDS read.
template <int EPI>
__global__ __launch_bounds__(512, 2)
void k_gemm2(const unsigned short* __restrict__ A, const unsigned short* __restrict__ B,
             const float* __restrict__ bias, float* __restrict__ C,
             const float* __restrict__ resid, const float* __restrict__ gatep,
             int K, int NT_N, int Nout, int ldc) {
  __shared__ alignas(16) unsigned short sm[73728];
  const int tid = threadIdx.x;
  const int lane = tid & 63, wid = tid >> 6;
  const int wm = wid >> 1, wn = wid & 1;
  const int fr = lane & 15, kg = lane >> 4;
  // XCD-bijective block swizzle (grid % 8 == 0 for all three GEMMs)
  const int nwg = gridDim.x;
  const int wg = ((int)blockIdx.x & 7) * (nwg >> 3) + ((int)blockIdx.x >> 3);
  const int m0 = (wg / NT_N) * 256, n0 = (wg % NT_N) * 128;
  const int NT = K >> 6;

  // pre-swizzled global staging sources (per-lane)
  const unsigned short* asrc[4];
  const unsigned short* bsrc[2];
#pragma unroll
  for (int li = 0; li < 4; ++li) {
    const int gi = li * 512 + tid, r = gi >> 3, q = gi & 7;
    asrc[li] = A + (size_t)(m0 + r) * K + ((q ^ (r & 7)) << 3);
  }
#pragma unroll
  for (int li = 0; li < 2; ++li) {
    const int gi = li * 512 + tid, r = gi >> 3, q = gi & 7;
    bsrc[li] = B + (size_t)(n0 + r) * K + ((q ^ (r & 7)) << 3);
  }
  const int wlds = wid * 64;

  f32x4 acc[4][4] = {};

  // prologue: stage K-tiles 0 and 1
  {
    unsigned short* b0 = sm;
    unsigned short* b1 = sm + 24576;
#pragma unroll
    for (int li = 0; li < 4; ++li) gload16(asrc[li], b0 + ((li * 512 + wlds) << 3));
#pragma unroll
    for (int li = 0; li < 2; ++li) gload16(bsrc[li], b0 + 16384 + ((li * 512 + wlds) << 3));
#pragma unroll
    for (int li = 0; li < 4; ++li) gload16(asrc[li] + 64, b1 + ((li * 512 + wlds) << 3));
#pragma unroll
    for (int li = 0; li < 2; ++li) gload16(bsrc[li] + 64, b1 + 16384 + ((li * 512 + wlds) << 3));
  }
  asm volatile("s_waitcnt vmcnt(6)" ::: "memory");
  __builtin_amdgcn_s_barrier();

  int bc_i = 0;
  for (int t = 0; t < NT; ++t) {
    unsigned short* bc = sm + bc_i * 24576;
    const int bn_i = (bc_i + 2 >= 3) ? (bc_i - 1) : (bc_i + 2);
    unsigned short* bnx = sm + bn_i * 24576;
    const bool st = (t + 2) < NT;
    const int koff = (t + 2) << 6;

    // ---- phase 0: ds-read A(mf0-1)+B(all), stage half of t+2, MFMA quadrant 0
    bf16x8 a0[2][2], bfv[4][2];
#pragma unroll
    for (int mf = 0; mf < 2; ++mf)
#pragma unroll
      for (int kk = 0; kk < 2; ++kk)
        a0[mf][kk] = *(const bf16x8*)(bc + (wm * 64 + mf * 16 + fr) * 64 +
                                      (((kk * 4 + kg) ^ (fr & 7)) << 3));
#pragma unroll
    for (int nf = 0; nf < 4; ++nf)
#pragma unroll
      for (int kk = 0; kk < 2; ++kk)
        bfv[nf][kk] = *(const bf16x8*)(bc + 16384 + (wn * 64 + nf * 16 + fr) * 64 +
                                       (((kk * 4 + kg) ^ (fr & 7)) << 3));
    if (st) {
      gload16(asrc[0] + koff, bnx + ((0 * 512 + wlds) << 3));
      gload16(asrc[1] + koff, bnx + ((1 * 512 + wlds) << 3));
      gload16(bsrc[0] + koff, bnx + 16384 + ((0 * 512 + wlds) << 3));
    }
    __builtin_amdgcn_s_barrier();
    asm volatile("s_waitcnt lgkmcnt(0)" ::: "memory");
    __builtin_amdgcn_s_setprio(1);
#pragma unroll
    for (int mf = 0; mf < 2; ++mf)
#pragma unroll
      for (int nf = 0; nf < 4; ++nf)
#pragma unroll
        for (int kk = 0; kk < 2; ++kk)
          acc[mf][nf] = __builtin_amdgcn_mfma_f32_16x16x32_bf16(a0[mf][kk], bfv[nf][kk],
                                                                acc[mf][nf], 0, 0, 0);
    __builtin_amdgcn_s_setprio(0);
    __builtin_amdgcn_s_barrier();

    // ---- phase 1: ds-read A(mf2-3), stage rest of t+2, MFMA quadrant 1
    bf16x8 a1[2][2];
#pragma unroll
    for (int mf = 0; mf < 2; ++mf)
#pragma unroll
      for (int kk = 0; kk < 2; ++kk)
        a1[mf][kk] = *(const bf16x8*)(bc + (wm * 64 + (mf + 2) * 16 + fr) * 64 +
                                      (((kk * 4 + kg) ^ (fr & 7)) << 3));
    if (st) {
      gload16(asrc[2] + koff, bnx + ((2 * 512 + wlds) << 3));
      gload16(asrc[3] + koff, bnx + ((3 * 512 + wlds) << 3));
      gload16(bsrc[1] + koff, bnx + 16384 + ((1 * 512 + wlds) << 3));
    }
    __builtin_amdgcn_s_barrier();
    asm volatile("s_waitcnt lgkmcnt(0)" ::: "memory");
    __builtin_amdgcn_s_setprio(1);
#pragma unroll
    for (int mf = 0; mf < 2; ++mf)
#pragma unroll
      for (int nf = 0; nf < 4; ++nf)
#pragma unroll
        for (int kk = 0; kk < 2; ++kk)
          acc[mf + 2][nf] = __builtin_amdgcn_mfma_f32_16x16x32_bf16(a1[mf][kk], bfv[nf][kk],
                                                                    acc[mf + 2][nf], 0, 0, 0);
    __builtin_amdgcn_s_setprio(0);
    if (st) asm volatile("s_waitcnt vmcnt(6)" ::: "memory");
    else    asm volatile("s_waitcnt vmcnt(0)" ::: "memory");
    __builtin_amdgcn_s_barrier();
    bc_i = (bc_i + 1 >= 3) ? 0 : (bc_i + 1);
  }

  // epilogue
  const float rg = (EPI == 2) ? gatep[0] : 0.f;
#pragma unroll
  for (int nf = 0; nf < 4; ++nf) {
    const int col = n0 + wn * 64 + nf * 16 + fr;
    if (col >= Nout) continue;
    const float bv = bias[col];
#pragma unroll
    for (int mf = 0; mf < 4; ++mf) {
      const int rowb = m0 + wm * 64 + mf * 16 + kg * 4;
#pragma unroll
      for (int r = 0; r < 4; ++r) {
        const size_t o = (size_t)(rowb + r) * ldc + col;
        float v = acc[mf][nf][r] + bv;
        if (EPI == 2) v = resid[o] + rg * v;
        C[o] = v;
      }
    }
  }
}

// ---------------- depthwise causal conv(4) + silu -> bf16 ----------------
__global__ __launch_bounds__(256) void k_dwconv(const float* __restrict__ xz,
                                                const float* __restrict__ cw,
                                                const float* __restrict__ cb,
                                                unsigned short* __restrict__ out) {
  const int idx = blockIdx.x * 256 + threadIdx.x;  // < MROWS*DI
  const int c = idx % DI;
  const int bl = idx / DI;
  const int lpos = bl & (LLEN - 1);
  float acc = cb[c];
  const float* w4 = cw + c * 4;
#pragma unroll
  for (int k = 0; k < 4; ++k) {
    const int ll = lpos - 3 + k;
    if (ll >= 0) acc = fmaf(w4[k], xz[(size_t)(bl - 3 + k) * N2 + c], acc);
  }
  const float s = acc / (1.f + expf(-acc));
  out[idx] = f2bf(s);
}

// ---------------- prep: normalize+pack B/C as bf16 in place, alpha compact ------
__global__ __launch_bounds__(256) void k_prep(float* __restrict__ xp,
                                              const unsigned short* __restrict__ xc,
                                              const float* __restrict__ A_log,
                                              const float* __restrict__ l2ab,
                                              const float* __restrict__ l2b,
                                              const float* __restrict__ se,
                                              float* __restrict__ al) {
  const int blk = blockIdx.x;               // MROWS*6
  const int w = threadIdx.x >> 6, lane = threadIdx.x & 63;
  const int bl = blk / 6, hq = blk % 6;
  const int h = hq * 4 + w;
  const size_t pbase = (size_t)bl * NP + h * 129;
  float bs = xp[pbase + 1 + lane];
  float cs = xp[pbase + 65 + lane];
  float xv = bf2f(xc[(size_t)bl * DI + h * DH + lane]);
  float sb = bs * bs, sc = cs * cs, sx = xv;
#pragma unroll
  for (int o = 32; o; o >>= 1) {
    sb += __shfl_xor(sb, o);
    sc += __shfl_xor(sc, o);
    sx += __shfl_xor(sx, o);
  }
  const float nb = fmaxf(sqrtf(sb), 1e-12f);
  const float nc = fmaxf(sqrtf(sc), 1e-12f);
  const float bn = bs / nb, cn = cs / nc;
  const float blo = __shfl(bn, lane * 2, 64), bhi = __shfl(bn, lane * 2 + 1, 64);
  const float clo = __shfl(cn, lane * 2, 64), chi = __shfl(cn, lane * 2 + 1, 64);
  if (lane < 32) {
    ((unsigned int*)(xp + pbase + 1))[lane]  = (unsigned int)f2bf(blo) | ((unsigned int)f2bf(bhi) << 16);
    ((unsigned int*)(xp + pbase + 33))[lane] = (unsigned int)f2bf(clo) | ((unsigned int)f2bf(chi) << 16);
  }
  const float sumB2 = sb / (nb * nb);
  const float xmean = sx * (1.f / 64.f);
  const float dt = xp[pbase];
  const float sp = (dt > 20.f) ? dt : log1pf(expf(dt));
  const float Ac = fminf(fmaxf(A_log[h], -2.3f), -0.01f);
  const float aa = expf(Ac * sp);
  const float one_a = 1.f - aa;
  const float pe = one_a * one_a * xmean * xmean * sumB2 * (1.f / 64.f);
  const float ns = pe / (se[h] + 1e-6f);
  const float beta = exp2f(fminf(fmaxf(l2b[h], -2.f), 2.f));
  const float boost = fmaxf(tanhf(beta * ns), 0.f);
  const float ab = 1.f - exp2f(fminf(fmaxf(l2ab[h], -3.32f), -0.015f));
  const float alpha = fminf(fmaxf(ab + (1.f - ab) * boost, 0.01f), 0.999f);
  if (lane == 0) {
    const int b = bl >> 11, l = bl & (LLEN - 1);
    al[(((size_t)b * NH + h) << 11) + l] = alpha;
  }
}

// ---------------- chunked scan, stage 1: intra-chunk Y + local state -----------
__global__ __launch_bounds__(256) void k_chunk1(
    const float* __restrict__ xp, const unsigned short* __restrict__ xcg,
    const float* __restrict__ al, float* __restrict__ xz,
    unsigned short* __restrict__ Hbuf, float* __restrict__ Dc) {
  const int blk = blockIdx.x;          // bh*16 + c
  const int bh = blk >> 4, c = blk & 15;
  const int b = bh / NH, h = bh % NH;
  const int tid = threadIdx.x, w = tid >> 6, lane = tid & 63;
  const int fr = lane & 15, kg = lane >> 4;
  const int rbase = b * LLEN + c * QC;

  __shared__ float lc[QC], ia[QC], escl[QC];
  __shared__ float wtot[2];
  __shared__ alignas(16) unsigned short XT[64][152];   // [d][u]
  __shared__ alignas(16) unsigned short BsT[64][152];  // [s][u] (scaled)
  __shared__ alignas(16) unsigned short Pt[128][88];   // [t][u-local] per u-tile

  float a = 1.f, la = 0.f;
  if (tid < QC) { a = al[(size_t)bh * LLEN + c * QC + tid]; la = __logf(a); }
  float s = la;
#pragma unroll
  for (int o = 1; o < 64; o <<= 1) { float t2 = __shfl_up(s, o); if (lane >= o) s += t2; }
  if (tid < QC && lane == 63) wtot[w] = s;
  __syncthreads();
  if (tid < QC) { lc[tid] = s + ((w == 1) ? wtot[0] : 0.f); ia[tid] = 1.f - a; }
  __syncthreads();
  const float lcE = lc[QC - 1];
  if (tid < QC) escl[tid] = __expf(lcE - lc[tid]) * ia[tid];
  if (tid == 0) Dc[blk] = __expf(lcE);
  __syncthreads();

  {
    const int r8 = tid >> 3, q8 = tid & 7;
#pragma unroll
    for (int it = 0; it < 4; ++it) {
      const int u = it * 32 + r8;
      uint4 xv = *(const uint4*)(xcg + (size_t)(rbase + u) * DI + h * DH + q8 * 8);
      const unsigned short* xs = (const unsigned short*)&xv;
#pragma unroll
      for (int j = 0; j < 8; ++j) XT[q8 * 8 + j][u] = xs[j];
      const unsigned int* bp = (const unsigned int*)(xp + (size_t)(rbase + u) * NP + h * 129 + 1) + q8 * 4;
      const float e = escl[u];
#pragma unroll
      for (int q = 0; q < 4; ++q) {
        unsigned int dv = bp[q];
        BsT[q8 * 8 + q * 2 + 0][u] = f2bf(bf2f((unsigned short)(dv & 0xffff)) * e);
        BsT[q8 * 8 + q * 2 + 1][u] = f2bf(bf2f((unsigned short)(dv >> 16)) * e);
      }
    }
  }
  bf16x8 cf[2][2];
#pragma unroll
  for (int fi = 0; fi < 2; ++fi)
#pragma unroll
    for (int kk = 0; kk < 2; ++kk) {
      const int t = w * 32 + fi * 16 + fr;
      const unsigned int* p = (const unsigned int*)(xp + (size_t)(rbase + t) * NP + h * 129 + 33) + kk * 16 + kg * 4;
      union { unsigned int u[4]; bf16x8 v; } uv;
      uv.u[0] = p[0]; uv.u[1] = p[1]; uv.u[2] = p[2]; uv.u[3] = p[3];
      cf[fi][kk] = uv.v;
    }
  __syncthreads();

  float lct[2][4];
#pragma unroll
  for (int fi = 0; fi < 2; ++fi)
#pragma unroll
    for (int r = 0; r < 4; ++r) lct[fi][r] = lc[w * 32 + fi * 16 + kg * 4 + r];

  f32x4 yacc[2][4] = {};
  f32x4 hacc[4] = {};
#pragma unroll
  for (int ut = 0; ut < 2; ++ut) {
    f32x4 g[2][4] = {};
#pragma unroll
    for (int kk = 0; kk < 2; ++kk)
#pragma unroll
      for (int fj = 0; fj < 4; ++fj) {
        const int u = ut * 64 + fj * 16 + fr;
        const unsigned int* p = (const unsigned int*)(xp + (size_t)(rbase + u) * NP + h * 129 + 1) + kk * 16 + kg * 4;
        union { unsigned int uu[4]; bf16x8 v; } uv;
        uv.uu[0] = p[0]; uv.uu[1] = p[1]; uv.uu[2] = p[2]; uv.uu[3] = p[3];
#pragma unroll
        for (int fi = 0; fi < 2; ++fi)
          g[fi][fj] = __builtin_amdgcn_mfma_f32_16x16x32_bf16(cf[fi][kk], uv.v, g[fi][fj], 0, 0, 0);
      }
#pragma unroll
    for (int fi = 0; fi < 2; ++fi)
#pragma unroll
      for (int fj = 0; fj < 4; ++fj) {
        const int u = ut * 64 + fj * 16 + fr;
        const float lcu = lc[u], iau = ia[u];
#pragma unroll
        for (int r = 0; r < 4; ++r) {
          const int t = w * 32 + fi * 16 + kg * 4 + r;
          const float v = (t >= u) ? g[fi][fj][r] * __expf(lct[fi][r] - lcu) * iau : 0.f;
          Pt[t][fj * 16 + fr] = f2bf(v);
        }
      }
#pragma unroll
    for (int kk = 0; kk < 2; ++kk) {
      bf16x8 xf[4];
#pragma unroll
      for (int fj = 0; fj < 4; ++fj)
        xf[fj] = *(const bf16x8*)&XT[fj * 16 + fr][ut * 64 + kk * 32 + kg * 8];
      bf16x8 pf[2];
#pragma unroll
      for (int fi = 0; fi < 2; ++fi)
        pf[fi] = *(const bf16x8*)&Pt[w * 32 + fi * 16 + fr][kk * 32 + kg * 8];
#pragma unroll
      for (int fi = 0; fi < 2; ++fi)
#pragma unroll
        for (int fj = 0; fj < 4; ++fj)
          yacc[fi][fj] = __builtin_amdgcn_mfma_f32_16x16x32_bf16(pf[fi], xf[fj], yacc[fi][fj], 0, 0, 0);
      const bf16x8 xh = *(const bf16x8*)&XT[w * 16 + fr][ut * 64 + kk * 32 + kg * 8];
#pragma unroll
      for (int fi = 0; fi < 4; ++fi) {
        const bf16x8 bs = *(const bf16x8*)&BsT[fi * 16 + fr][ut * 64 + kk * 32 + kg * 8];
        hacc[fi] = __builtin_amdgcn_mfma_f32_16x16x32_bf16(bs, xh, hacc[fi], 0, 0, 0);
      }
    }
  }
#pragma unroll
  for (int fi = 0; fi < 2; ++fi)
#pragma unroll
    for (int fj = 0; fj < 4; ++fj)
#pragma unroll
      for (int r = 0; r < 4; ++r) {
        const int t = w * 32 + fi * 16 + kg * 4 + r;
        const int d = fj * 16 + fr;
        xz[(size_t)(rbase + t) * N2 + h * DH + d] = yacc[fi][fj][r];
      }
  const int dcol = w * 16 + fr;
#pragma unroll
  for (int fi = 0; fi < 4; ++fi) {
    ushort4 pk;
    pk.x = f2bf(hacc[fi][0]); pk.y = f2bf(hacc[fi][1]);
    pk.z = f2bf(hacc[fi][2]); pk.w = f2bf(hacc[fi][3]);
    *(ushort4*)(Hbuf + ((size_t)blk * 64 + dcol) * 64 + fi * 16 + kg * 4) = pk;
  }
}

// ---------------- chunked scan, stage 2: carry across chunks (in place) --------
__global__ __launch_bounds__(256) void k_carry(unsigned short* __restrict__ Hbuf,
                                               const float* __restrict__ Dc) {
  const int bh = blockIdx.x, tid = threadIdx.x;
  float carry[16];
#pragma unroll
  for (int j = 0; j < 16; ++j) carry[j] = 0.f;
  for (int c = 0; c < NCHUNK; ++c) {
    unsigned short* p = Hbuf + (((size_t)(bh * NCHUNK + c)) << 12) + tid * 16;
    const uint4 v0 = *(const uint4*)(p);
    const uint4 v1 = *(const uint4*)(p + 8);
    const unsigned short* hs0 = (const unsigned short*)&v0;
    const unsigned short* hs1 = (const unsigned short*)&v1;
    float hl[16];
#pragma unroll
    for (int j = 0; j < 8; ++j) { hl[j] = bf2f(hs0[j]); hl[8 + j] = bf2f(hs1[j]); }
    uint4 o0, o1;
    unsigned short* os0 = (unsigned short*)&o0;
    unsigned short* os1 = (unsigned short*)&o1;
#pragma unroll
    for (int j = 0; j < 8; ++j) { os0[j] = f2bf(carry[j]); os1[j] = f2bf(carry[8 + j]); }
    *(uint4*)(p) = o0;
    *(uint4*)(p + 8) = o1;
    const float dc = Dc[bh * NCHUNK + c];
#pragma unroll
    for (int j = 0; j < 16; ++j) carry[j] = fmaf(dc, carry[j], hl[j]);
  }
}

// ---------------- chunked scan, stage 3: inter-chunk Y + fused gating ----------
__global__ __launch_bounds__(256) void k_chunk2(
    const float* __restrict__ xp, const float* __restrict__ al,
    const unsigned short* __restrict__ Hbuf, const float* __restrict__ xz,
    unsigned short* __restrict__ xcg) {
  const int blk = blockIdx.x;
  const int bh = blk >> 4, c = blk & 15;
  const int b = bh / NH, h = bh % NH;
  const int tid = threadIdx.x, w = tid >> 6, lane = tid & 63;
  const int fr = lane & 15, kg = lane >> 4;
  const int rbase = b * LLEN + c * QC;
  __shared__ float lc[QC];
  __shared__ float wtot[2];
  float a = 1.f, la = 0.f;
  if (tid < QC) { a = al[(size_t)bh * LLEN + c * QC + tid]; la = __logf(a); }
  float s = la;
#pragma unroll
  for (int o = 1; o < 64; o <<= 1) { float t2 = __shfl_up(s, o); if (lane >= o) s += t2; }
  if (tid < QC && lane == 63) wtot[w] = s;
  __syncthreads();
  if (tid < QC) lc[tid] = s + ((w == 1) ? wtot[0] : 0.f);
  __syncthreads();
  bf16x8 cf[2][2];
#pragma unroll
  for (int fi = 0; fi < 2; ++fi) {
    const int t = w * 32 + fi * 16 + fr;
    const float sc = __expf(lc[t]);
#pragma unroll
    for (int kk = 0; kk < 2; ++kk) {
      const unsigned int* p = (const unsigned int*)(xp + (size_t)(rbase + t) * NP + h * 129 + 33) + kk * 16 + kg * 4;
      union { unsigned short us[8]; bf16x8 v; } uv;
#pragma unroll
      for (int q = 0; q < 4; ++q) {
        const unsigned int dv = p[q];
        uv.us[2 * q]     = f2bf(bf2f((unsigned short)(dv & 0xffff)) * sc);
        uv.us[2 * q + 1] = f2bf(bf2f((unsigned short)(dv >> 16)) * sc);
      }
      cf[fi][kk] = uv.v;
    }
  }
  bf16x8 hf[4][2];
#pragma unroll
  for (int fj = 0; fj < 4; ++fj)
#pragma unroll
    for (int kk = 0; kk < 2; ++kk) {
      const uint4 v = *(const uint4*)(Hbuf + ((size_t)blk * 64 + fj * 16 + fr) * 64 + kk * 32 + kg * 8);
      hf[fj][kk] = *(const bf16x8*)&v;
    }
  f32x4 y[2][4] = {};
#pragma unroll
  for (int kk = 0; kk < 2; ++kk)
#pragma unroll
    for (int fi = 0; fi < 2; ++fi)
#pragma unroll
      for (int fj = 0; fj < 4; ++fj)
        y[fi][fj] = __builtin_amdgcn_mfma_f32_16x16x32_bf16(cf[fi][kk], hf[fj][kk], y[fi][fj], 0, 0, 0);
#pragma unroll
  for (int fi = 0; fi < 2; ++fi)
#pragma unroll
    for (int fj = 0; fj < 4; ++fj)
#pragma unroll
      for (int r = 0; r < 4; ++r) {
        const int t = w * 32 + fi * 16 + kg * 4 + r;
        const int d = fj * 16 + fr;
        const size_t rowg = (size_t)(rbase + t);
        const float yv = y[fi][fj][r] + xz[rowg * N2 + h * DH + d];
        const float zv = xz[rowg * N2 + DI + h * DH + d];
        const float g = yv * (zv / (1.f + __expf(-zv)));
        xcg[rowg * DI + h * DH + d] = f2bf(g);
      }
}

extern "C" void kernel_launch(void* const* d_in, const int* in_sizes, int n_in,
                              void* d_out, int out_size, void* d_ws, size_t ws_size,
                              hipStream_t stream) {
  const float* hs     = (const float*)d_in[0];
  const float* norm_w = (const float*)d_in[1];
  const float* in_w   = (const float*)d_in[2];
  const float* in_b   = (const float*)d_in[3];
  const float* cw     = (const float*)d_in[4];
  const float* cb     = (const float*)d_in[5];
  const float* xw     = (const float*)d_in[6];
  const float* xb     = (const float*)d_in[7];
  const float* A_log  = (const float*)d_in[8];
  const float* l2ab   = (const float*)d_in[9];
  const float* l2b    = (const float*)d_in[10];
  const float* se     = (const float*)d_in[11];
  const float* ow     = (const float*)d_in[12];
  const float* ob     = (const float*)d_in[13];
  const float* rg     = (const float*)d_in[14];
  float* out = (float*)d_out;

  char* ws = (char*)d_ws;
  unsigned short* xnorm = (unsigned short*)(ws);
  unsigned short* wA    = (unsigned short*)(ws + 33554432ull);
  unsigned short* wX    = (unsigned short*)(ws + 46137344ull);
  unsigned short* wO    = (unsigned short*)(ws + 55967744ull);
  float* xz             = (float*)(ws + 62259200ull);
  float* xp             = (float*)(ws + 162922496ull);
  unsigned short* xcg   = xnorm;
  unsigned short* Hbuf  = wA;
  float* al             = (float*)(ws + 46137344ull);
  float* Dc             = (float*)(ws + 46137344ull + 786432ull);

  k_w2bf<<<(N2 * DMODEL) / 256, 256, 0, stream>>>(in_w, wA, N2 * DMODEL, N2 * DMODEL);
  k_w2bf<<<(NP_PAD * DI) / 256, 256, 0, stream>>>(xw, wX, NP * DI, NP_PAD * DI);
  k_w2bf<<<(DMODEL * DI) / 256, 256, 0, stream>>>(ow, wO, DMODEL * DI, DMODEL * DI);

  k_rmsnorm<<<MROWS, 256, 0, stream>>>(hs, norm_w, xnorm);
  // in_proj: 32 m-tiles x 24 n-tiles = 768 blocks
  k_gemm2<0><<<768, 512, 0, stream>>>(xnorm, wA, in_b, xz, nullptr, nullptr,
                                      DMODEL, 24, N2, N2);
  k_dwconv<<<(MROWS * DI) / 256, 256, 0, stream>>>(xz, cw, cb, xcg);
  // x_proj: 32 x 25 = 800 blocks (wX padded to 3200 rows)
  k_gemm2<0><<<800, 512, 0, stream>>>(xcg, wX, xb, xp, nullptr, nullptr,
                                      DI, 25, NP, NP);
  k_prep<<<MROWS * 6, 256, 0, stream>>>(xp, xcg, A_log, l2ab, l2b, se, al);

  k_chunk1<<<BB * NH * NCHUNK, 256, 0, stream>>>(xp, xcg, al, xz, Hbuf, Dc);
  k_carry<<<BB * NH, 256, 0, stream>>>(Hbuf, Dc);
  k_chunk2<<<BB * NH * NCHUNK, 256, 0, stream>>>(xp, al, Hbuf, xz, xcg);

  // out_proj: 32 x 16 = 512 blocks
  k_gemm2<2><<<512, 512, 0, stream>>>(xcg, wO, ob, out, hs, rg,
                                      DI, 16, DMODEL, DMODEL);
}

// Round 5
// 583.714 us; speedup vs baseline: 3.4447x; 1.0404x over previous
//
#include <hip/hip_runtime.h>
#include <stdint.h>

// Problem constants
#define BB 4
#define LLEN 2048
#define DMODEL 2048
#define NH 24
#define DH 64
#define SS 64
#define DI 1536          // NH*DH
#define N2 3072          // 2*DI
#define NP 3096          // NH*(1+2*S)
#define NP_PAD 3200      // weight rows padded (zero rows 3096..3199)
#define MROWS 8192       // BB*LLEN
#define NCHUNK 16
#define QC 128           // chunk length

using bf16x8 = __bf16 __attribute__((ext_vector_type(8)));
using f32x4  = float __attribute__((ext_vector_type(4)));

__device__ __forceinline__ unsigned short f2bf(float f) {
  union { float f; unsigned int u; } v; v.f = f;
  unsigned int u = v.u + 0x7fffu + ((v.u >> 16) & 1u);
  return (unsigned short)(u >> 16);
}
__device__ __forceinline__ float bf2f(unsigned short h) {
  union { unsigned int u; float f; } v; v.u = ((unsigned int)h) << 16;
  return v.f;
}

__device__ __forceinline__ void gload16(const void* g, void* l) {
  __builtin_amdgcn_global_load_lds(
    reinterpret_cast<const __attribute__((address_space(1))) void*>(reinterpret_cast<uintptr_t>(g)),
    reinterpret_cast<__attribute__((address_space(3))) void*>((uint32_t)(reinterpret_cast<uintptr_t>(l))),
    16, 0, 0);
}

// ---------------- fp32 -> bf16 weight convert (with zero row padding) ----------
__global__ __launch_bounds__(256) void k_w2bf(const float* __restrict__ s,
                                              unsigned short* __restrict__ d,
                                              int n_src, int n_dst) {
  int i = blockIdx.x * 256 + threadIdx.x;
  if (i < n_dst) d[i] = (i < n_src) ? f2bf(s[i]) : (unsigned short)0;
}

// ---------------- RMSNorm -> bf16 ----------------
__global__ __launch_bounds__(256) void k_rmsnorm(const float* __restrict__ hs,
                                                 const float* __restrict__ w,
                                                 unsigned short* __restrict__ out) {
  const int row = blockIdx.x;
  const int t = threadIdx.x;
  const float* x = hs + (size_t)row * DMODEL;
  float4 v0 = reinterpret_cast<const float4*>(x)[t * 2 + 0];
  float4 v1 = reinterpret_cast<const float4*>(x)[t * 2 + 1];
  float ss = v0.x * v0.x + v0.y * v0.y + v0.z * v0.z + v0.w * v0.w +
             v1.x * v1.x + v1.y * v1.y + v1.z * v1.z + v1.w * v1.w;
#pragma unroll
  for (int o = 32; o; o >>= 1) ss += __shfl_xor(ss, o);
  __shared__ float red[4];
  if ((t & 63) == 0) red[t >> 6] = ss;
  __syncthreads();
  ss = red[0] + red[1] + red[2] + red[3];
  const float r = rsqrtf(ss * (1.0f / DMODEL) + 1.1920928955078125e-07f);
  float4 w0 = reinterpret_cast<const float4*>(w)[t * 2 + 0];
  float4 w1 = reinterpret_cast<const float4*>(w)[t * 2 + 1];
  union { unsigned short u[8]; uint4 v; } pk;
  pk.u[0] = f2bf(v0.x * r * w0.x); pk.u[1] = f2bf(v0.y * r * w0.y);
  pk.u[2] = f2bf(v0.z * r * w0.z); pk.u[3] = f2bf(v0.w * r * w0.w);
  pk.u[4] = f2bf(v1.x * r * w1.x); pk.u[5] = f2bf(v1.y * r * w1.y);
  pk.u[6] = f2bf(v1.z * r * w1.z); pk.u[7] = f2bf(v1.w * r * w1.w);
  *reinterpret_cast<uint4*>(out + (size_t)row * DMODEL + t * 8) = pk.v;
}

// ---------------- 8-phase 256x256 bf16 NT GEMM (m201-style template) -----------
// C[m,n] = sum_k A[m,k]*B[n,k] (+bias); EPI 2: C = resid + rg*(acc+bias).
// 512 threads = 8 waves (2M x 4N); per-wave 128x64 output split as rows
// [wm*64, +64) U [128+wm*64, +64) so A-half0 frees after phase 2.
// LDS 128KB = 2 dbuf x (A 32KB + B 32KB). BK=64, 2 K-tiles/iter, 8 phases/iter.
// Counted vmcnt(6) at phases 4/8 only (3 half-tiles = 6 loads in flight).
template <int EPI>
__global__ __launch_bounds__(512, 2)
void k_gemm3(const unsigned short* __restrict__ A, const unsigned short* __restrict__ B,
             const float* __restrict__ bias, float* __restrict__ C,
             const float* __restrict__ resid, const float* __restrict__ gatep,
             int K, int NT_N, int Nout, int ldc) {
  __shared__ alignas(16) unsigned short sm[65536];  // 128 KB
  const int tid = threadIdx.x;
  const int lane = tid & 63, wid = tid >> 6;
  const int wm = wid >> 2, wn = wid & 3;
  const int fr = lane & 15, kg = lane >> 4;
  // XCD-bijective block swizzle (all grids % 8 == 0)
  const int nwg = gridDim.x;
  const int wg = ((int)blockIdx.x & 7) * (nwg >> 3) + ((int)blockIdx.x >> 3);
  const int m0 = (wg / NT_N) * 256, n0 = (wg % NT_N) * 256;
  const int NI = K >> 7;   // iters; 2 K-tiles (BK=64) per iter

  // pre-swizzled per-lane global staging sources (granule q ^= row&7)
  const unsigned short* asrc[4];
  const unsigned short* bsrc[4];
#pragma unroll
  for (int li = 0; li < 4; ++li) {
    const int gi = li * 512 + tid, r = gi >> 3, q = gi & 7;
    asrc[li] = A + (size_t)(m0 + r) * K + ((q ^ (r & 7)) << 3);
    bsrc[li] = B + (size_t)(n0 + r) * K + ((q ^ (r & 7)) << 3);
  }
  const int wlds = wid * 64;

  // stage one 16KB half (2 x gload16): op half h of A/B into buf, k-offset ko
#define STG_A(buf, h, ko)                                                     \
  { unsigned short* d_ = sm + (buf) * 32768;                                  \
    gload16(asrc[(h)*2 + 0] + (ko), d_ + ((((h)*2 + 0) * 512 + wlds) << 3));  \
    gload16(asrc[(h)*2 + 1] + (ko), d_ + ((((h)*2 + 1) * 512 + wlds) << 3)); }
#define STG_B(buf, h, ko)                                                     \
  { unsigned short* d_ = sm + (buf) * 32768 + 16384;                          \
    gload16(bsrc[(h)*2 + 0] + (ko), d_ + ((((h)*2 + 0) * 512 + wlds) << 3));  \
    gload16(bsrc[(h)*2 + 1] + (ko), d_ + ((((h)*2 + 1) * 512 + wlds) << 3)); }

  f32x4 acc[8][4] = {};

  // prologue: tile0 -> buf0 (all 4 halves), tile1 -> buf1 (B0,B1,A0) = 14 loads
  STG_B(0, 0, 0) STG_B(0, 1, 0) STG_A(0, 0, 0) STG_A(0, 1, 0)
  STG_B(1, 0, 64) STG_B(1, 1, 64) STG_A(1, 0, 64)
  asm volatile("s_waitcnt vmcnt(6)" ::: "memory");   // drain tile0's 8
  __builtin_amdgcn_s_barrier();

  bf16x8 bfv[4][2], af[2][2];
  // A frag row (within tile) for frag f: f<4 -> wm*64+f*16 ; else 128+wm*64+(f-4)*16
#define ARD(buf, f, kk)                                                        \
  (*(const bf16x8*)(sm + (buf) * 32768 +                                      \
      (((f) < 4 ? wm * 64 + (f) * 16 : 128 + wm * 64 + ((f) - 4) * 16) + fr) * 64 + \
      ((((kk) * 4 + kg) ^ (fr & 7)) << 3)))
#define BRD(buf, nf, kk)                                                       \
  (*(const bf16x8*)(sm + (buf) * 32768 + 16384 + (wn * 64 + (nf) * 16 + fr) * 64 + \
      ((((kk) * 4 + kg) ^ (fr & 7)) << 3)))
#define MFMA16(sp)                                                             \
  __builtin_amdgcn_s_setprio(1);                                              \
  _Pragma("unroll") for (int mf = 0; mf < 2; ++mf)                             \
  _Pragma("unroll") for (int nf = 0; nf < 4; ++nf)                            \
  _Pragma("unroll") for (int kk = 0; kk < 2; ++kk)                            \
    acc[(sp)*2 + mf][nf] = __builtin_amdgcn_mfma_f32_16x16x32_bf16(           \
        af[mf][kk], bfv[nf][kk], acc[(sp)*2 + mf][nf], 0, 0, 0);              \
  __builtin_amdgcn_s_setprio(0);

  for (int i = 0; i < NI; ++i) {
    const bool nx = (i + 1 < NI);
    const int ko1 = (2 * i + 1) << 6, ko2 = (2 * i + 2) << 6, ko3 = (2 * i + 3) << 6;

    // ---- phases 1-4: tile 2i from buf0 ----
    // ph1: read all B + A frags 0-1 ; stage t(2i+1) A-half1 -> buf1
#pragma unroll
    for (int nf = 0; nf < 4; ++nf) { bfv[nf][0] = BRD(0, nf, 0); bfv[nf][1] = BRD(0, nf, 1); }
    af[0][0] = ARD(0, 0, 0); af[0][1] = ARD(0, 0, 1);
    af[1][0] = ARD(0, 1, 0); af[1][1] = ARD(0, 1, 1);
    STG_A(1, 1, ko1)
    __builtin_amdgcn_s_barrier();
    asm volatile("s_waitcnt lgkmcnt(0)" ::: "memory");
    MFMA16(0)
    __builtin_amdgcn_s_barrier();
    // ph2: A frags 2-3 ; stage t(2i+2) B-half0 -> buf0 (B freed after ph1)
    af[0][0] = ARD(0, 2, 0); af[0][1] = ARD(0, 2, 1);
    af[1][0] = ARD(0, 3, 0); af[1][1] = ARD(0, 3, 1);
    if (nx) STG_B(0, 0, ko2)
    __builtin_amdgcn_s_barrier();
    asm volatile("s_waitcnt lgkmcnt(0)" ::: "memory");
    MFMA16(1)
    __builtin_amdgcn_s_barrier();
    // ph3: A frags 4-5 ; stage t(2i+2) B-half1
    af[0][0] = ARD(0, 4, 0); af[0][1] = ARD(0, 4, 1);
    af[1][0] = ARD(0, 5, 0); af[1][1] = ARD(0, 5, 1);
    if (nx) STG_B(0, 1, ko2)
    __builtin_amdgcn_s_barrier();
    asm volatile("s_waitcnt lgkmcnt(0)" ::: "memory");
    MFMA16(2)
    __builtin_amdgcn_s_barrier();
    // ph4: A frags 6-7 ; stage t(2i+2) A-half0 (freed after ph2); vmcnt guard t(2i+1)
    af[0][0] = ARD(0, 6, 0); af[0][1] = ARD(0, 6, 1);
    af[1][0] = ARD(0, 7, 0); af[1][1] = ARD(0, 7, 1);
    if (nx) STG_A(0, 0, ko2)
    __builtin_amdgcn_s_barrier();
    asm volatile("s_waitcnt lgkmcnt(0)" ::: "memory");
    MFMA16(3)
    if (nx) { asm volatile("s_waitcnt vmcnt(6)" ::: "memory"); }
    else    { asm volatile("s_waitcnt vmcnt(0)" ::: "memory"); }
    __builtin_amdgcn_s_barrier();

    // ---- phases 5-8: tile 2i+1 from buf1 ----
    // ph5: read all B + A frags 0-1 ; stage t(2i+2) A-half1 (freed after ph4)
#pragma unroll
    for (int nf = 0; nf < 4; ++nf) { bfv[nf][0] = BRD(1, nf, 0); bfv[nf][1] = BRD(1, nf, 1); }
    af[0][0] = ARD(1, 0, 0); af[0][1] = ARD(1, 0, 1);
    af[1][0] = ARD(1, 1, 0); af[1][1] = ARD(1, 1, 1);
    if (nx) STG_A(0, 1, ko2)
    __builtin_amdgcn_s_barrier();
    asm volatile("s_waitcnt lgkmcnt(0)" ::: "memory");
    MFMA16(0)
    __builtin_amdgcn_s_barrier();
    // ph6: A 2-3 ; stage t(2i+3) B-half0 -> buf1 (B freed after ph5)
    af[0][0] = ARD(1, 2, 0); af[0][1] = ARD(1, 2, 1);
    af[1][0] = ARD(1, 3, 0); af[1][1] = ARD(1, 3, 1);
    if (nx) STG_B(1, 0, ko3)
    __builtin_amdgcn_s_barrier();
    asm volatile("s_waitcnt lgkmcnt(0)" ::: "memory");
    MFMA16(1)
    __builtin_amdgcn_s_barrier();
    // ph7: A 4-5 ; stage t(2i+3) B-half1
    af[0][0] = ARD(1, 4, 0); af[0][1] = ARD(1, 4, 1);
    af[1][0] = ARD(1, 5, 0); af[1][1] = ARD(1, 5, 1);
    if (nx) STG_B(1, 1, ko3)
    __builtin_amdgcn_s_barrier();
    asm volatile("s_waitcnt lgkmcnt(0)" ::: "memory");
    MFMA16(2)
    __builtin_amdgcn_s_barrier();
    // ph8: A 6-7 ; stage t(2i+3) A-half0 (freed after ph6); vmcnt guard t(2i+2)
    af[0][0] = ARD(1, 6, 0); af[0][1] = ARD(1, 6, 1);
    af[1][0] = ARD(1, 7, 0); af[1][1] = ARD(1, 7, 1);
    if (nx) STG_A(1, 0, ko3)
    __builtin_amdgcn_s_barrier();
    asm volatile("s_waitcnt lgkmcnt(0)" ::: "memory");
    MFMA16(3)
    if (nx) { asm volatile("s_waitcnt vmcnt(6)" ::: "memory"); }
    __builtin_amdgcn_s_barrier();
  }

  // epilogue
  const float rg = (EPI == 2) ? gatep[0] : 0.f;
#pragma unroll
  for (int nf = 0; nf < 4; ++nf) {
    const int col = n0 + wn * 64 + nf * 16 + fr;
    if (col >= Nout) continue;
    const float bv = bias[col];
#pragma unroll
    for (int mf = 0; mf < 8; ++mf) {
      const int rowb = m0 + ((mf < 4) ? wm * 64 + mf * 16
                                      : 128 + wm * 64 + (mf - 4) * 16) + kg * 4;
#pragma unroll
      for (int r = 0; r < 4; ++r) {
        const size_t o = (size_t)(rowb + r) * ldc + col;
        float v = acc[mf][nf][r] + bv;
        if (EPI == 2) v = resid[o] + rg * v;
        C[o] = v;
      }
    }
  }
#undef STG_A
#undef STG_B
#undef ARD
#undef BRD
#undef MFMA16
}

// ---------------- depthwise causal conv(4) + silu -> bf16 ----------------
__global__ __launch_bounds__(256) void k_dwconv(const float* __restrict__ xz,
                                                const float* __restrict__ cw,
                                                const float* __restrict__ cb,
                                                unsigned short* __restrict__ out) {
  const int idx = blockIdx.x * 256 + threadIdx.x;  // < MROWS*DI
  const int c = idx % DI;
  const int bl = idx / DI;
  const int lpos = bl & (LLEN - 1);
  float acc = cb[c];
  const float* w4 = cw + c * 4;
#pragma unroll
  for (int k = 0; k < 4; ++k) {
    const int ll = lpos - 3 + k;
    if (ll >= 0) acc = fmaf(w4[k], xz[(size_t)(bl - 3 + k) * N2 + c], acc);
  }
  const float s = acc / (1.f + expf(-acc));
  out[idx] = f2bf(s);
}

// ---------------- prep: normalize+pack B/C as bf16 in place, alpha compact ------
__global__ __launch_bounds__(256) void k_prep(float* __restrict__ xp,
                                              const unsigned short* __restrict__ xc,
                                              const float* __restrict__ A_log,
                                              const float* __restrict__ l2ab,
                                              const float* __restrict__ l2b,
                                              const float* __restrict__ se,
                                              float* __restrict__ al) {
  const int blk = blockIdx.x;               // MROWS*6
  const int w = threadIdx.x >> 6, lane = threadIdx.x & 63;
  const int bl = blk / 6, hq = blk % 6;
  const int h = hq * 4 + w;
  const size_t pbase = (size_t)bl * NP + h * 129;
  float bs = xp[pbase + 1 + lane];
  float cs = xp[pbase + 65 + lane];
  float xv = bf2f(xc[(size_t)bl * DI + h * DH + lane]);
  float sb = bs * bs, sc = cs * cs, sx = xv;
#pragma unroll
  for (int o = 32; o; o >>= 1) {
    sb += __shfl_xor(sb, o);
    sc += __shfl_xor(sc, o);
    sx += __shfl_xor(sx, o);
  }
  const float nb = fmaxf(sqrtf(sb), 1e-12f);
  const float nc = fmaxf(sqrtf(sc), 1e-12f);
  const float bn = bs / nb, cn = cs / nc;
  const float blo = __shfl(bn, lane * 2, 64), bhi = __shfl(bn, lane * 2 + 1, 64);
  const float clo = __shfl(cn, lane * 2, 64), chi = __shfl(cn, lane * 2 + 1, 64);
  if (lane < 32) {
    ((unsigned int*)(xp + pbase + 1))[lane]  = (unsigned int)f2bf(blo) | ((unsigned int)f2bf(bhi) << 16);
    ((unsigned int*)(xp + pbase + 33))[lane] = (unsigned int)f2bf(clo) | ((unsigned int)f2bf(chi) << 16);
  }
  const float sumB2 = sb / (nb * nb);
  const float xmean = sx * (1.f / 64.f);
  const float dt = xp[pbase];
  const float sp = (dt > 20.f) ? dt : log1pf(expf(dt));
  const float Ac = fminf(fmaxf(A_log[h], -2.3f), -0.01f);
  const float aa = expf(Ac * sp);
  const float one_a = 1.f - aa;
  const float pe = one_a * one_a * xmean * xmean * sumB2 * (1.f / 64.f);
  const float ns = pe / (se[h] + 1e-6f);
  const float beta = exp2f(fminf(fmaxf(l2b[h], -2.f), 2.f));
  const float boost = fmaxf(tanhf(beta * ns), 0.f);
  const float ab = 1.f - exp2f(fminf(fmaxf(l2ab[h], -3.32f), -0.015f));
  const float alpha = fminf(fmaxf(ab + (1.f - ab) * boost, 0.01f), 0.999f);
  if (lane == 0) {
    const int b = bl >> 11, l = bl & (LLEN - 1);
    al[(((size_t)b * NH + h) << 11) + l] = alpha;
  }
}

// ---------------- chunked scan, stage 1: intra-chunk Y + local state -----------
__global__ __launch_bounds__(256) void k_chunk1(
    const float* __restrict__ xp, const unsigned short* __restrict__ xcg,
    const float* __restrict__ al, float* __restrict__ xz,
    unsigned short* __restrict__ Hbuf, float* __restrict__ Dc) {
  const int blk = blockIdx.x;          // bh*16 + c
  const int bh = blk >> 4, c = blk & 15;
  const int b = bh / NH, h = bh % NH;
  const int tid = threadIdx.x, w = tid >> 6, lane = tid & 63;
  const int fr = lane & 15, kg = lane >> 4;
  const int rbase = b * LLEN + c * QC;

  __shared__ float lc[QC], ia[QC], escl[QC];
  __shared__ float wtot[2];
  __shared__ alignas(16) unsigned short XT[64][152];   // [d][u]
  __shared__ alignas(16) unsigned short BsT[64][152];  // [s][u] (scaled)
  __shared__ alignas(16) unsigned short Pt[128][88];   // [t][u-local] per u-tile

  float a = 1.f, la = 0.f;
  if (tid < QC) { a = al[(size_t)bh * LLEN + c * QC + tid]; la = __logf(a); }
  float s = la;
#pragma unroll
  for (int o = 1; o < 64; o <<= 1) { float t2 = __shfl_up(s, o); if (lane >= o) s += t2; }
  if (tid < QC && lane == 63) wtot[w] = s;
  __syncthreads();
  if (tid < QC) { lc[tid] = s + ((w == 1) ? wtot[0] : 0.f); ia[tid] = 1.f - a; }
  __syncthreads();
  const float lcE = lc[QC - 1];
  if (tid < QC) escl[tid] = __expf(lcE - lc[tid]) * ia[tid];
  if (tid == 0) Dc[blk] = __expf(lcE);
  __syncthreads();

  {
    const int r8 = tid >> 3, q8 = tid & 7;
#pragma unroll
    for (int it = 0; it < 4; ++it) {
      const int u = it * 32 + r8;
      uint4 xv = *(const uint4*)(xcg + (size_t)(rbase + u) * DI + h * DH + q8 * 8);
      const unsigned short* xs = (const unsigned short*)&xv;
#pragma unroll
      for (int j = 0; j < 8; ++j) XT[q8 * 8 + j][u] = xs[j];
      const unsigned int* bp = (const unsigned int*)(xp + (size_t)(rbase + u) * NP + h * 129 + 1) + q8 * 4;
      const float e = escl[u];
#pragma unroll
      for (int q = 0; q < 4; ++q) {
        unsigned int dv = bp[q];
        BsT[q8 * 8 + q * 2 + 0][u] = f2bf(bf2f((unsigned short)(dv & 0xffff)) * e);
        BsT[q8 * 8 + q * 2 + 1][u] = f2bf(bf2f((unsigned short)(dv >> 16)) * e);
      }
    }
  }
  bf16x8 cf[2][2];
#pragma unroll
  for (int fi = 0; fi < 2; ++fi)
#pragma unroll
    for (int kk = 0; kk < 2; ++kk) {
      const int t = w * 32 + fi * 16 + fr;
      const unsigned int* p = (const unsigned int*)(xp + (size_t)(rbase + t) * NP + h * 129 + 33) + kk * 16 + kg * 4;
      union { unsigned int u[4]; bf16x8 v; } uv;
      uv.u[0] = p[0]; uv.u[1] = p[1]; uv.u[2] = p[2]; uv.u[3] = p[3];
      cf[fi][kk] = uv.v;
    }
  __syncthreads();

  float lct[2][4];
#pragma unroll
  for (int fi = 0; fi < 2; ++fi)
#pragma unroll
    for (int r = 0; r < 4; ++r) lct[fi][r] = lc[w * 32 + fi * 16 + kg * 4 + r];

  f32x4 yacc[2][4] = {};
  f32x4 hacc[4] = {};
#pragma unroll
  for (int ut = 0; ut < 2; ++ut) {
    f32x4 g[2][4] = {};
#pragma unroll
    for (int kk = 0; kk < 2; ++kk)
#pragma unroll
      for (int fj = 0; fj < 4; ++fj) {
        const int u = ut * 64 + fj * 16 + fr;
        const unsigned int* p = (const unsigned int*)(xp + (size_t)(rbase + u) * NP + h * 129 + 1) + kk * 16 + kg * 4;
        union { unsigned int uu[4]; bf16x8 v; } uv;
        uv.uu[0] = p[0]; uv.uu[1] = p[1]; uv.uu[2] = p[2]; uv.uu[3] = p[3];
#pragma unroll
        for (int fi = 0; fi < 2; ++fi)
          g[fi][fj] = __builtin_amdgcn_mfma_f32_16x16x32_bf16(cf[fi][kk], uv.v, g[fi][fj], 0, 0, 0);
      }
#pragma unroll
    for (int fi = 0; fi < 2; ++fi)
#pragma unroll
      for (int fj = 0; fj < 4; ++fj) {
        const int u = ut * 64 + fj * 16 + fr;
        const float lcu = lc[u], iau = ia[u];
#pragma unroll
        for (int r = 0; r < 4; ++r) {
          const int t = w * 32 + fi * 16 + kg * 4 + r;
          const float v = (t >= u) ? g[fi][fj][r] * __expf(lct[fi][r] - lcu) * iau : 0.f;
          Pt[t][fj * 16 + fr] = f2bf(v);
        }
      }
#pragma unroll
    for (int kk = 0; kk < 2; ++kk) {
      bf16x8 xf[4];
#pragma unroll
      for (int fj = 0; fj < 4; ++fj)
        xf[fj] = *(const bf16x8*)&XT[fj * 16 + fr][ut * 64 + kk * 32 + kg * 8];
      bf16x8 pf[2];
#pragma unroll
      for (int fi = 0; fi < 2; ++fi)
        pf[fi] = *(const bf16x8*)&Pt[w * 32 + fi * 16 + fr][kk * 32 + kg * 8];
#pragma unroll
      for (int fi = 0; fi < 2; ++fi)
#pragma unroll
        for (int fj = 0; fj < 4; ++fj)
          yacc[fi][fj] = __builtin_amdgcn_mfma_f32_16x16x32_bf16(pf[fi], xf[fj], yacc[fi][fj], 0, 0, 0);
      const bf16x8 xh = *(const bf16x8*)&XT[w * 16 + fr][ut * 64 + kk * 32 + kg * 8];
#pragma unroll
      for (int fi = 0; fi < 4; ++fi) {
        const bf16x8 bs = *(const bf16x8*)&BsT[fi * 16 + fr][ut * 64 + kk * 32 + kg * 8];
        hacc[fi] = __builtin_amdgcn_mfma_f32_16x16x32_bf16(bs, xh, hacc[fi], 0, 0, 0);
      }
    }
  }
#pragma unroll
  for (int fi = 0; fi < 2; ++fi)
#pragma unroll
    for (int fj = 0; fj < 4; ++fj)
#pragma unroll
      for (int r = 0; r < 4; ++r) {
        const int t = w * 32 + fi * 16 + kg * 4 + r;
        const int d = fj * 16 + fr;
        xz[(size_t)(rbase + t) * N2 + h * DH + d] = yacc[fi][fj][r];
      }
  const int dcol = w * 16 + fr;
#pragma unroll
  for (int fi = 0; fi < 4; ++fi) {
    ushort4 pk;
    pk.x = f2bf(hacc[fi][0]); pk.y = f2bf(hacc[fi][1]);
    pk.z = f2bf(hacc[fi][2]); pk.w = f2bf(hacc[fi][3]);
    *(ushort4*)(Hbuf + ((size_t)blk * 64 + dcol) * 64 + fi * 16 + kg * 4) = pk;
  }
}

// ---------------- chunked scan, stage 2: carry across chunks (in place) --------
__global__ __launch_bounds__(256) void k_carry(unsigned short* __restrict__ Hbuf,
                                               const float* __restrict__ Dc) {
  const int bh = blockIdx.x, tid = threadIdx.x;
  float carry[16];
#pragma unroll
  for (int j = 0; j < 16; ++j) carry[j] = 0.f;
  for (int c = 0; c < NCHUNK; ++c) {
    unsigned short* p = Hbuf + (((size_t)(bh * NCHUNK + c)) << 12) + tid * 16;
    const uint4 v0 = *(const uint4*)(p);
    const uint4 v1 = *(const uint4*)(p + 8);
    const unsigned short* hs0 = (const unsigned short*)&v0;
    const unsigned short* hs1 = (const unsigned short*)&v1;
    float hl[16];
#pragma unroll
    for (int j = 0; j < 8; ++j) { hl[j] = bf2f(hs0[j]); hl[8 + j] = bf2f(hs1[j]); }
    uint4 o0, o1;
    unsigned short* os0 = (unsigned short*)&o0;
    unsigned short* os1 = (unsigned short*)&o1;
#pragma unroll
    for (int j = 0; j < 8; ++j) { os0[j] = f2bf(carry[j]); os1[j] = f2bf(carry[8 + j]); }
    *(uint4*)(p) = o0;
    *(uint4*)(p + 8) = o1;
    const float dc = Dc[bh * NCHUNK + c];
#pragma unroll
    for (int j = 0; j < 16; ++j) carry[j] = fmaf(dc, carry[j], hl[j]);
  }
}

// ---------------- chunked scan, stage 3: inter-chunk Y + fused gating ----------
__global__ __launch_bounds__(256) void k_chunk2(
    const float* __restrict__ xp, const float* __restrict__ al,
    const unsigned short* __restrict__ Hbuf, const float* __restrict__ xz,
    unsigned short* __restrict__ xcg) {
  const int blk = blockIdx.x;
  const int bh = blk >> 4, c = blk & 15;
  const int b = bh / NH, h = bh % NH;
  const int tid = threadIdx.x, w = tid >> 6, lane = tid & 63;
  const int fr = lane & 15, kg = lane >> 4;
  const int rbase = b * LLEN + c * QC;
  __shared__ float lc[QC];
  __shared__ float wtot[2];
  float a = 1.f, la = 0.f;
  if (tid < QC) { a = al[(size_t)bh * LLEN + c * QC + tid]; la = __logf(a); }
  float s = la;
#pragma unroll
  for (int o = 1; o < 64; o <<= 1) { float t2 = __shfl_up(s, o); if (lane >= o) s += t2; }
  if (tid < QC && lane == 63) wtot[w] = s;
  __syncthreads();
  if (tid < QC) lc[tid] = s + ((w == 1) ? wtot[0] : 0.f);
  __syncthreads();
  bf16x8 cf[2][2];
#pragma unroll
  for (int fi = 0; fi < 2; ++fi) {
    const int t = w * 32 + fi * 16 + fr;
    const float sc = __expf(lc[t]);
#pragma unroll
    for (int kk = 0; kk < 2; ++kk) {
      const unsigned int* p = (const unsigned int*)(xp + (size_t)(rbase + t) * NP + h * 129 + 33) + kk * 16 + kg * 4;
      union { unsigned short us[8]; bf16x8 v; } uv;
#pragma unroll
      for (int q = 0; q < 4; ++q) {
        const unsigned int dv = p[q];
        uv.us[2 * q]     = f2bf(bf2f((unsigned short)(dv & 0xffff)) * sc);
        uv.us[2 * q + 1] = f2bf(bf2f((unsigned short)(dv >> 16)) * sc);
      }
      cf[fi][kk] = uv.v;
    }
  }
  bf16x8 hf[4][2];
#pragma unroll
  for (int fj = 0; fj < 4; ++fj)
#pragma unroll
    for (int kk = 0; kk < 2; ++kk) {
      const uint4 v = *(const uint4*)(Hbuf + ((size_t)blk * 64 + fj * 16 + fr) * 64 + kk * 32 + kg * 8);
      hf[fj][kk] = *(const bf16x8*)&v;
    }
  f32x4 y[2][4] = {};
#pragma unroll
  for (int kk = 0; kk < 2; ++kk)
#pragma unroll
    for (int fi = 0; fi < 2; ++fi)
#pragma unroll
      for (int fj = 0; fj < 4; ++fj)
        y[fi][fj] = __builtin_amdgcn_mfma_f32_16x16x32_bf16(cf[fi][kk], hf[fj][kk], y[fi][fj], 0, 0, 0);
#pragma unroll
  for (int fi = 0; fi < 2; ++fi)
#pragma unroll
    for (int fj = 0; fj < 4; ++fj)
#pragma unroll
      for (int r = 0; r < 4; ++r) {
        const int t = w * 32 + fi * 16 + kg * 4 + r;
        const int d = fj * 16 + fr;
        const size_t rowg = (size_t)(rbase + t);
        const float yv = y[fi][fj][r] + xz[rowg * N2 + h * DH + d];
        const float zv = xz[rowg * N2 + DI + h * DH + d];
        const float g = yv * (zv / (1.f + __expf(-zv)));
        xcg[rowg * DI + h * DH + d] = f2bf(g);
      }
}

extern "C" void kernel_launch(void* const* d_in, const int* in_sizes, int n_in,
                              void* d_out, int out_size, void* d_ws, size_t ws_size,
                              hipStream_t stream) {
  const float* hs     = (const float*)d_in[0];
  const float* norm_w = (const float*)d_in[1];
  const float* in_w   = (const float*)d_in[2];
  const float* in_b   = (const float*)d_in[3];
  const float* cw     = (const float*)d_in[4];
  const float* cb     = (const float*)d_in[5];
  const float* xw     = (const float*)d_in[6];
  const float* xb     = (const float*)d_in[7];
  const float* A_log  = (const float*)d_in[8];
  const float* l2ab   = (const float*)d_in[9];
  const float* l2b    = (const float*)d_in[10];
  const float* se     = (const float*)d_in[11];
  const float* ow     = (const float*)d_in[12];
  const float* ob     = (const float*)d_in[13];
  const float* rg     = (const float*)d_in[14];
  float* out = (float*)d_out;

  char* ws = (char*)d_ws;
  unsigned short* xnorm = (unsigned short*)(ws);
  unsigned short* wA    = (unsigned short*)(ws + 33554432ull);
  unsigned short* wX    = (unsigned short*)(ws + 46137344ull);
  unsigned short* wO    = (unsigned short*)(ws + 55967744ull);
  float* xz             = (float*)(ws + 62259200ull);
  float* xp             = (float*)(ws + 162922496ull);
  unsigned short* xcg   = xnorm;
  unsigned short* Hbuf  = wA;
  float* al             = (float*)(ws + 46137344ull);
  float* Dc             = (float*)(ws + 46137344ull + 786432ull);

  k_w2bf<<<(N2 * DMODEL) / 256, 256, 0, stream>>>(in_w, wA, N2 * DMODEL, N2 * DMODEL);
  k_w2bf<<<(NP_PAD * DI) / 256, 256, 0, stream>>>(xw, wX, NP * DI, NP_PAD * DI);
  k_w2bf<<<(DMODEL * DI) / 256, 256, 0, stream>>>(ow, wO, DMODEL * DI, DMODEL * DI);

  k_rmsnorm<<<MROWS, 256, 0, stream>>>(hs, norm_w, xnorm);
  // in_proj: 32 m-tiles x 12 n-tiles = 384 blocks
  k_gemm3<0><<<384, 512, 0, stream>>>(xnorm, wA, in_b, xz, nullptr, nullptr,
                                      DMODEL, 12, N2, N2);
  k_dwconv<<<(MROWS * DI) / 256, 256, 0, stream>>>(xz, cw, cb, xcg);
  // x_proj: 32 x 13 = 416 blocks (last n-tile reads past wX into wO; cols masked)
  k_gemm3<0><<<416, 512, 0, stream>>>(xcg, wX, xb, xp, nullptr, nullptr,
                                      DI, 13, NP, NP);
  k_prep<<<MROWS * 6, 256, 0, stream>>>(xp, xcg, A_log, l2ab, l2b, se, al);

  k_chunk1<<<BB * NH * NCHUNK, 256, 0, stream>>>(xp, xcg, al, xz, Hbuf, Dc);
  k_carry<<<BB * NH, 256, 0, stream>>>(Hbuf, Dc);
  k_chunk2<<<BB * NH * NCHUNK, 256, 0, stream>>>(xp, al, Hbuf, xz, xcg);

  // out_proj: 32 x 8 = 256 blocks
  k_gemm3<2><<<256, 512, 0, stream>>>(xcg, wO, ob, out, hs, rg,
                                      DI, 8, DMODEL, DMODEL);
}